// Round 8
// baseline (587.154 us; speedup 1.0000x reference)
//
#include <hip/hip_runtime.h>

// ---------------- problem constants ----------------
constexpr int cN0 = 200000, cN1 = 50000, cN2 = 10000;
constexpr int cE0 = 800000, cE1 = 160000;
constexpr int GD  = 144;       // 32+16+16+16+64
constexpr int KP  = 160;       // padded K for MFMA (col 144 = bias-multiplier lane)
constexpr int HID = 256, OUTD = 128;
constexpr int KT  = 512;       // tail K = 2*HID

constexpr int WN   = 64;                 // dsts per bucket
constexpr int CAP  = 1280;               // bucket capacity (lambda~1024, +8 sigma)
constexpr int NBK0 = (cN1 + WN - 1) / WN;   // 782
constexpr int NBK1 = (cN2 + WN - 1) / WN;   // 157
constexpr int NBTOT = 2 * NBK0 + 2 * NBK1;  // 1878
constexpr int GEMM_RB = (50048 + 255) / 256; // 196 row-blocks
constexpr int TAIL_NB = cN2 / 16;            // 625
constexpr size_t UPLANE = (size_t)50048 * KP;

constexpr int CHUNK = 4096;                      // edges per bucketize block
constexpr int NCH0  = (cE0 + CHUNK - 1) / CHUNK; // 196
constexpr int NCH1  = (cE1 + CHUNK - 1) / CHUNK; // 40

typedef __attribute__((ext_vector_type(8))) short bf16x8;
typedef __attribute__((ext_vector_type(4))) float f32x4;

__device__ __forceinline__ ushort f2bf(float f) {
  union { float f; unsigned u; } v; v.f = f;
  unsigned r = (v.u + 0x7FFFu + ((v.u >> 16) & 1u)) >> 16;
  return (ushort)r;
}
__device__ __forceinline__ float bf2f(ushort u) {
  union { unsigned u; float f; } v; v.u = ((unsigned)u) << 16;
  return v.f;
}

// ---------------- bucketize v3: 4096-edge chunks, 256 thr, 6 blocks/CU ------
// packed words are UNSIGNED: bits 0..25 src, bits 26..31 local dst (0..63).
__global__ __launch_bounds__(256)
void bucketize_v3(const int* __restrict__ s0, const int* __restrict__ d0,
                  const int* __restrict__ s1, const int* __restrict__ d1,
                  const int* __restrict__ s2, const int* __restrict__ d2,
                  const int* __restrict__ s3, const int* __restrict__ d3,
                  int* __restrict__ bfill, unsigned* __restrict__ packed) {
  __shared__ unsigned sed[CHUNK];                  // 16 KB sorted edges
  __shared__ int lcnt[NBK0], lstart[NBK0], lfill[NBK0];
  __shared__ int wsums[4];
  int bid = blockIdx.x, tid = threadIdx.x;
  const int *sp, *dp; int E, bb, blk, NB;
  if (bid < NCH0)             { sp = s0; dp = d0; E = cE0; bb = 0;               blk = bid;                 NB = NBK0; }
  else if (bid < 2*NCH0)      { sp = s1; dp = d1; E = cE0; bb = NBK0;            blk = bid - NCH0;          NB = NBK0; }
  else if (bid < 2*NCH0+NCH1) { sp = s2; dp = d2; E = cE1; bb = 2*NBK0;          blk = bid - 2*NCH0;        NB = NBK1; }
  else                        { sp = s3; dp = d3; E = cE1; bb = 2*NBK0 + NBK1;   blk = bid - 2*NCH0 - NCH1; NB = NBK1; }
  int base = blk * CHUNK;
  int n = min(CHUNK, E - base);

  for (int i = tid; i < NB; i += 256) { lcnt[i] = 0; lfill[i] = 0; }
  __syncthreads();
  // phase 1: count buckets
  for (int i = tid; i < n; i += 256)
    atomicAdd(&lcnt[dp[base + i] >> 6], 1);
  __syncthreads();
  // phase 2: exclusive scan lcnt -> lstart (4 elems/thread, 4 waves)
  {
    int lane = tid & 63, wv = tid >> 6;
    int i0 = tid * 4;
    int v[4], s = 0;
    #pragma unroll
    for (int j = 0; j < 4; ++j) {
      v[j] = (i0 + j < NB) ? lcnt[i0 + j] : 0;
      s += v[j];
    }
    int tot = s;
    #pragma unroll
    for (int off = 1; off < 64; off <<= 1) {
      int t = __shfl_up(s, off);
      if (lane >= off) s += t;
    }
    if (lane == 63) wsums[wv] = s;
    __syncthreads();
    if (wv == 0 && lane < 4) {
      int xch = wsums[lane];
      #pragma unroll
      for (int off = 1; off < 4; off <<= 1) {
        int t = __shfl_up(xch, off);
        if (lane >= off) xch += t;
      }
      wsums[lane] = xch;
    }
    __syncthreads();
    int excl = (wv > 0 ? wsums[wv - 1] : 0) + (s - tot);
    #pragma unroll
    for (int j = 0; j < 4; ++j) {
      if (i0 + j < NB) lstart[i0 + j] = excl;
      excl += v[j];
    }
  }
  __syncthreads();
  // phase 3: scatter into LDS sorted-by-bucket order (edges re-read, L1-hot)
  for (int i = tid; i < n; i += 256) {
    int dd = dp[base + i];
    int b = dd >> 6;
    int p = atomicAdd(&lfill[b], 1);
    sed[lstart[b] + p] = (unsigned)sp[base + i] | ((unsigned)(dd & 63) << 26);
  }
  __syncthreads();
  // phase 4: one global atomic per (block,bucket); contiguous run copy-out
  int lane = tid & 63, wv = tid >> 6;
  for (int b = wv; b < NB; b += 4) {
    int cnt = lcnt[b];
    if (cnt == 0) continue;
    int gb0;
    if (lane == 0) gb0 = atomicAdd(&bfill[bb + b], cnt);
    gb0 = __shfl(gb0, 0);
    int st = lstart[b];
    for (int i = lane; i < cnt; i += 64) {
      int gp = gb0 + i;
      if (gp < CAP) packed[(size_t)(bb + b) * CAP + gp] = sed[st + i];
    }
  }
}

// ---------------- fused layer-0: LDS sort + embedding mean-agg -> u bf16 ----
__global__ __launch_bounds__(256)
void agg0_fused(const int* __restrict__ x,
                const float* __restrict__ s_t0, const float* __restrict__ s_t1,
                const float* __restrict__ s_t2, const float* __restrict__ s_t3,
                const float* __restrict__ s_t4,
                const float* __restrict__ c_t0, const float* __restrict__ c_t1,
                const float* __restrict__ c_t2, const float* __restrict__ c_t3,
                const float* __restrict__ c_t4,
                const int* __restrict__ bfill, const unsigned* __restrict__ packed,
                ushort* __restrict__ u) {
  __shared__ unsigned lvals[CAP];
  __shared__ int lsrc[CAP];
  __shared__ int lcnt[WN], lstart[WN], lfill[WN];
  __shared__ int xst[4][64 * 5];
  int tid = threadIdx.x, w = tid >> 6, lane = tid & 63;
  int br = blockIdx.x / NBK0;
  int bk = blockIdx.x - br * NBK0;
  int gb = blockIdx.x;               // == br*NBK0 + bk (seg bases 0, NBK0)
  int dst0 = bk * WN;
  int nd = min(WN, cN1 - dst0);

  const float* t0 = br ? c_t0 : s_t0;
  const float* t1 = br ? c_t1 : s_t1;
  const float* t2 = br ? c_t2 : s_t2;
  const float* t3 = br ? c_t3 : s_t3;
  const float* t4 = br ? c_t4 : s_t4;
  const float* gbase; int gxs, gstride;
  if (lane < 8)       { gbase = t0 + lane * 4;        gxs = 0; gstride = 32; }
  else if (lane < 12) { gbase = t1 + (lane - 8) * 4;  gxs = 1; gstride = 16; }
  else if (lane < 16) { gbase = t2 + (lane - 12) * 4; gxs = 2; gstride = 16; }
  else if (lane < 20) { gbase = t3 + (lane - 16) * 4; gxs = 3; gstride = 16; }
  else if (lane < 36) { gbase = t4 + (lane - 20) * 4; gxs = 4; gstride = 64; }
  else                { gbase = t0;                   gxs = 0; gstride = 0;  }

  if (tid < WN) { lcnt[tid] = 0; lfill[tid] = 0; }
  __syncthreads();
  int ec = min(bfill[gb], CAP);
  for (int i = tid; i < ec; i += 256) {
    unsigned v = packed[(size_t)gb * CAP + i];
    lvals[i] = v;
    atomicAdd(&lcnt[v >> 26], 1);
  }
  __syncthreads();
  if (tid < 64) {
    int c = lcnt[tid]; int s = c;
    #pragma unroll
    for (int off = 1; off < 64; off <<= 1) {
      int t = __shfl_up(s, off);
      if (lane >= off) s += t;
    }
    lstart[tid] = s - c;
  }
  __syncthreads();
  for (int i = tid; i < ec; i += 256) {
    unsigned v = lvals[i];
    int l = (int)(v >> 26);
    int p = atomicAdd(&lfill[l], 1);
    lsrc[lstart[l] + p] = (int)(v & 0x3FFFFFFu);
  }
  __syncthreads();

  int* xstw = xst[w];
  for (int d = w; d < nd; d += 4) {
    int deg = lcnt[d], beg = lstart[d];
    float4 acc = make_float4(0.f, 0.f, 0.f, 0.f);
    for (int off = 0; off < deg; off += 64) {
      int nn = min(64, deg - off);
      if (lane < nn) {
        int s = lsrc[beg + off + lane];
        const int* xp = x + (size_t)s * 5;
        int v0 = xp[0], v1 = xp[1], v2 = xp[2], v3 = xp[3], v4 = xp[4];
        int* q = xstw + lane * 5;
        q[0] = v0; q[1] = v1; q[2] = v2; q[3] = v3; q[4] = v4;
      }
      int e = 0;
      for (; e + 8 <= nn; e += 8) {
        int rr[8];
        #pragma unroll
        for (int q = 0; q < 8; ++q) rr[q] = xstw[(e + q) * 5 + gxs];
        float4 g[8];
        #pragma unroll
        for (int q = 0; q < 8; ++q)
          g[q] = *reinterpret_cast<const float4*>(gbase + (size_t)rr[q] * gstride);
        #pragma unroll
        for (int q = 0; q < 8; ++q) {
          acc.x += g[q].x; acc.y += g[q].y; acc.z += g[q].z; acc.w += g[q].w;
        }
      }
      for (; e < nn; ++e) {
        int r = xstw[e * 5 + gxs];
        const float4 g = *reinterpret_cast<const float4*>(gbase + (size_t)r * gstride);
        acc.x += g.x; acc.y += g.y; acc.z += g.z; acc.w += g.w;
      }
    }
    float invc = (deg > 0) ? 1.f / (float)deg : 0.f;
    int dg = dst0 + d;
    ushort* ur = u + (size_t)br * UPLANE + (size_t)dg * KP;
    if (lane < 36) {
      const int* xd = x + (size_t)dg * 5;
      const float4 sv = *reinterpret_cast<const float4*>(gbase + (size_t)xd[gxs] * gstride);
      float4 r;
      r.x = sv.x + acc.x * invc;
      r.y = sv.y + acc.y * invc;
      r.z = sv.z + acc.z * invc;
      r.w = sv.w + acc.w * invc;
      ushort4 o;
      o.x = f2bf(r.x); o.y = f2bf(r.y); o.z = f2bf(r.z); o.w = f2bf(r.w);
      *reinterpret_cast<ushort4*>(ur + lane * 4) = o;
    } else if (lane == 36) {
      ushort4 o;
      o.x = f2bf(deg > 0 ? 2.f : 1.f);   // bias multiplier feature (col 144)
      o.y = 0; o.z = 0; o.w = 0;
      *reinterpret_cast<ushort4*>(ur + 144) = o;
    } else if (lane < 40) {
      *reinterpret_cast<ushort4*>(ur + lane * 4) = make_ushort4(0, 0, 0, 0);
    }
  }
}

// ---------------- W_in transpose+bf16+pad (+bias in row 144) ----------------
__global__ __launch_bounds__(KP)
void build_wt2(const float* __restrict__ Ws, const float* __restrict__ Wc,
               const float* __restrict__ bs, const float* __restrict__ bc,
               ushort* __restrict__ Wt) {
  int br = blockIdx.x >> 8, n = blockIdx.x & 255, k = threadIdx.x;
  const float* W = br ? Wc : Ws;
  const float* b = br ? bc : bs;
  float v = (k < GD) ? W[(size_t)k * HID + n] : ((k == GD) ? b[n] : 0.f);
  Wt[(size_t)br * HID * KP + n * KP + k] = f2bf(v);
}

// ---------------- layer-0 MFMA GEMM: h1 = relu(u@Wt^T), bf16 out -----------
// block: 4 waves x 64 rows = 256 rows, 128-col half staged in LDS.
__global__ __launch_bounds__(256)
void gemm_mfma2(const ushort* __restrict__ U, const ushort* __restrict__ Wt,
                ushort* __restrict__ h1) {
  __shared__ ushort Wth[128][KP + 8];
  int bid = blockIdx.x, tid = threadIdx.x;
  int rowblk = bid % GEMM_RB;
  int half = (bid / GEMM_RB) & 1;
  int br = bid / (2 * GEMM_RB);
  const ushort* Wsrc = Wt + ((size_t)br * HID + half * 128) * KP;
  for (int i = tid; i < 128 * (KP / 8); i += 256) {
    int r = i / (KP / 8), g = i - r * (KP / 8);
    *reinterpret_cast<bf16x8*>(&Wth[r][g * 8]) =
        *reinterpret_cast<const bf16x8*>(Wsrc + (size_t)r * KP + g * 8);
  }
  __syncthreads();
  int w = tid >> 6, lane = tid & 63, l15 = lane & 15, lhi = lane >> 4;
  int rowbase = rowblk * 256 + w * 64;
  const ushort* Ubr = U + (size_t)br * UPLANE;
  f32x4 acc[4][8];
  #pragma unroll
  for (int rt = 0; rt < 4; ++rt)
    #pragma unroll
    for (int ct = 0; ct < 8; ++ct) acc[rt][ct] = (f32x4){0.f, 0.f, 0.f, 0.f};
  #pragma unroll
  for (int ks = 0; ks < 5; ++ks) {
    bf16x8 bfr[8];
    #pragma unroll
    for (int ct = 0; ct < 8; ++ct)
      bfr[ct] = *reinterpret_cast<const bf16x8*>(&Wth[ct * 16 + l15][lhi * 8 + ks * 32]);
    #pragma unroll
    for (int rt = 0; rt < 4; ++rt) {
      int ar = rowbase + rt * 16 + l15;
      if (ar > 50047) ar = 50047;
      bf16x8 af = *reinterpret_cast<const bf16x8*>(Ubr + (size_t)ar * KP + lhi * 8 + ks * 32);
      #pragma unroll
      for (int ct = 0; ct < 8; ++ct)
        acc[rt][ct] = __builtin_amdgcn_mfma_f32_16x16x32_bf16(af, bfr[ct], acc[rt][ct], 0, 0, 0);
    }
  }
  ushort* h1p = h1 + (size_t)br * cN1 * HID + half * 128;
  #pragma unroll
  for (int rt = 0; rt < 4; ++rt) {
    #pragma unroll
    for (int r = 0; r < 4; ++r) {
      int row = rowbase + rt * 16 + lhi * 4 + r;
      if (row >= cN1) continue;
      #pragma unroll
      for (int ct = 0; ct < 8; ++ct)
        h1p[(size_t)row * HID + ct * 16 + l15] = f2bf(fmaxf(acc[rt][ct][r], 0.f));
    }
  }
}

// ---------------- fused layer-1: LDS sort + h1 mean-agg -> V bf16 ----------
__global__ __launch_bounds__(256)
void agg1_fused(const ushort* __restrict__ h1, const int* __restrict__ bfill,
                const unsigned* __restrict__ packed, ushort* __restrict__ V) {
  __shared__ unsigned lvals[CAP];
  __shared__ int lsrc[CAP];
  __shared__ int lcnt[WN], lstart[WN], lfill[WN];
  int tid = threadIdx.x, w = tid >> 6, lane = tid & 63;
  int br = blockIdx.x / NBK1;
  int bk = blockIdx.x - br * NBK1;
  int gb = 2 * NBK0 + blockIdx.x;    // seg bases 2*NBK0, 2*NBK0+NBK1
  int dst0 = bk * WN;
  int nd = min(WN, cN2 - dst0);
  const ushort* h1p = h1 + (size_t)br * cN1 * HID;

  if (tid < WN) { lcnt[tid] = 0; lfill[tid] = 0; }
  __syncthreads();
  int ec = min(bfill[gb], CAP);
  for (int i = tid; i < ec; i += 256) {
    unsigned v = packed[(size_t)gb * CAP + i];
    lvals[i] = v;
    atomicAdd(&lcnt[v >> 26], 1);
  }
  __syncthreads();
  if (tid < 64) {
    int c = lcnt[tid]; int s = c;
    #pragma unroll
    for (int off = 1; off < 64; off <<= 1) {
      int t = __shfl_up(s, off);
      if (lane >= off) s += t;
    }
    lstart[tid] = s - c;
  }
  __syncthreads();
  for (int i = tid; i < ec; i += 256) {
    unsigned v = lvals[i];
    int l = (int)(v >> 26);
    int p = atomicAdd(&lfill[l], 1);
    lsrc[lstart[l] + p] = (int)(v & 0x3FFFFFFu);
  }
  __syncthreads();

  for (int d = w; d < nd; d += 4) {
    int deg = lcnt[d], beg = lstart[d];
    float4 acc = make_float4(0.f, 0.f, 0.f, 0.f);
    int e = 0;
    for (; e + 4 <= deg; e += 4) {
      int sA = lsrc[beg + e], sB = lsrc[beg + e + 1];
      int sC = lsrc[beg + e + 2], sD = lsrc[beg + e + 3];
      ushort4 hA = *reinterpret_cast<const ushort4*>(h1p + (size_t)sA * HID + lane * 4);
      ushort4 hB = *reinterpret_cast<const ushort4*>(h1p + (size_t)sB * HID + lane * 4);
      ushort4 hC = *reinterpret_cast<const ushort4*>(h1p + (size_t)sC * HID + lane * 4);
      ushort4 hD = *reinterpret_cast<const ushort4*>(h1p + (size_t)sD * HID + lane * 4);
      acc.x += bf2f(hA.x) + bf2f(hB.x) + bf2f(hC.x) + bf2f(hD.x);
      acc.y += bf2f(hA.y) + bf2f(hB.y) + bf2f(hC.y) + bf2f(hD.y);
      acc.z += bf2f(hA.z) + bf2f(hB.z) + bf2f(hC.z) + bf2f(hD.z);
      acc.w += bf2f(hA.w) + bf2f(hB.w) + bf2f(hC.w) + bf2f(hD.w);
    }
    for (; e < deg; ++e) {
      int s = lsrc[beg + e];
      ushort4 hv = *reinterpret_cast<const ushort4*>(h1p + (size_t)s * HID + lane * 4);
      acc.x += bf2f(hv.x); acc.y += bf2f(hv.y); acc.z += bf2f(hv.z); acc.w += bf2f(hv.w);
    }
    float invc = (deg > 0) ? 1.f / (float)deg : 0.f;
    int dg = dst0 + d;
    ushort4 dv = *reinterpret_cast<const ushort4*>(h1p + (size_t)dg * HID + lane * 4);
    ushort4 o;
    o.x = f2bf(bf2f(dv.x) + acc.x * invc);
    o.y = f2bf(bf2f(dv.y) + acc.y * invc);
    o.z = f2bf(bf2f(dv.z) + acc.z * invc);
    o.w = f2bf(bf2f(dv.w) + acc.w * invc);
    *reinterpret_cast<ushort4*>(V + (size_t)dg * KT + br * HID + lane * 4) = o;
  }
}

// ---------------- integration weight folding ----------------
__global__ __launch_bounds__(128)
void build_small(const float* __restrict__ Ws2c, const float* __restrict__ Wc2s,
                 const float* __restrict__ a1p, const float* __restrict__ a2p,
                 const float* __restrict__ b2p, float* __restrict__ M) {
  int r = blockIdx.x, c = threadIdx.x;
  float A1 = a1p[0], A2 = a2p[0], B2 = b2p[0];
  float c0 = 1.f - A2 - B2;
  float c1 = A2 + B2 * (1.f - A1);
  float c2 = A1 * B2;
  float s1 = 0.f, s4 = 0.f;
  for (int k = 0; k < 128; ++k) {
    s1 += Ws2c[r * 128 + k] * Wc2s[k * 128 + c];
    s4 += Wc2s[r * 128 + k] * Ws2c[k * 128 + c];
  }
  float eye = (r == c) ? c0 : 0.f;
  M[0 * 16384 + r * 128 + c] = c2 * s1 + eye;
  M[1 * 16384 + r * 128 + c] = c1 * Wc2s[r * 128 + c];
  M[2 * 16384 + r * 128 + c] = c1 * Ws2c[r * 128 + c];
  M[3 * 16384 + r * 128 + c] = c2 * s4 + eye;
}

__global__ __launch_bounds__(256)
void build_G(const float* __restrict__ Wout_s, const float* __restrict__ Wout_c,
             const float* __restrict__ M, ushort* __restrict__ Gt) {
  __shared__ float wr[128];
  int k = blockIdx.x, j = threadIdx.x;
  const float* wrow = (k < 256) ? &Wout_s[(size_t)k * 128] : &Wout_c[(size_t)(k - 256) * 128];
  if (j < 128) wr[j] = wrow[j];
  __syncthreads();
  const float* Mm = (j < 128) ? (k < 256 ? M : M + 16384)
                              : (k < 256 ? M + 2 * 16384 : M + 3 * 16384);
  int jj = j & 127;
  float s = 0.f;
  for (int t = 0; t < 128; ++t) s += wr[t] * Mm[t * 128 + jj];
  Gt[(size_t)j * KT + k] = f2bf(s);
}

__global__ __launch_bounds__(256)
void build_gvec(const float* __restrict__ b_s, const float* __restrict__ b_c,
                const float* __restrict__ M, float* __restrict__ gvec) {
  int j = threadIdx.x, jj = j & 127;
  const float* Ma = (j < 128) ? M : M + 2 * 16384;
  const float* Mb = (j < 128) ? M + 16384 : M + 3 * 16384;
  float s = 0.f;
  for (int t = 0; t < 128; ++t)
    s += b_s[t] * Ma[t * 128 + jj] + b_c[t] * Mb[t * 128 + jj];
  gvec[j] = s;
}

// ---------------- tail MFMA GEMM: out = V @ Gt^T + gvec ----------------
__global__ __launch_bounds__(64)
void tail_gemm(const ushort* __restrict__ V, const ushort* __restrict__ Gt,
               const float* __restrict__ gvec, float* __restrict__ out) {
  int lane = threadIdx.x;
  int l15 = lane & 15, lhi = lane >> 4;
  int rowW = blockIdx.x * 16;
  f32x4 acc[16];
  #pragma unroll
  for (int t = 0; t < 16; ++t) acc[t] = (f32x4){0.f, 0.f, 0.f, 0.f};
  const ushort* vp = V + (size_t)(rowW + l15) * KT + lhi * 8;
  const ushort* gp = Gt + (size_t)l15 * KT + lhi * 8;
  #pragma unroll
  for (int ks = 0; ks < 16; ++ks) {
    bf16x8 a = *reinterpret_cast<const bf16x8*>(vp + ks * 32);
    #pragma unroll
    for (int t = 0; t < 16; ++t) {
      bf16x8 b = *reinterpret_cast<const bf16x8*>(gp + (size_t)t * 16 * KT + ks * 32);
      acc[t] = __builtin_amdgcn_mfma_f32_16x16x32_bf16(a, b, acc[t], 0, 0, 0);
    }
  }
  int r0 = rowW + lhi * 4;
  #pragma unroll
  for (int t = 0; t < 16; ++t) {
    int col = t * 16 + l15;
    float gv = gvec[col];
    float* dst = (col < 128) ? out + (size_t)r0 * OUTD + col
                             : out + (size_t)cN2 * OUTD + (size_t)r0 * OUTD + (col - 128);
    #pragma unroll
    for (int r = 0; r < 4; ++r)
      dst[(size_t)r * OUTD] = acc[t][r] + gv;
  }
}

// ---------------- launch ----------------
extern "C" void kernel_launch(void* const* d_in, const int* in_sizes, int n_in,
                              void* d_out, int out_size, void* d_ws, size_t ws_size,
                              hipStream_t stream) {
  const int* x = (const int*)d_in[0];
  struct Branch {
    const int *e0s, *e0d, *e1s, *e1d;
    const float *t0, *t1, *t2, *t3, *t4, *Win, *bin, *Wout, *bout;
  };
  auto mk = [&](int b) {
    Branch B;
    B.e0s = (const int*)d_in[b + 0];
    B.e0d = (const int*)d_in[b + 1];
    B.e1s = (const int*)d_in[b + 2];
    B.e1d = (const int*)d_in[b + 3];
    B.t0  = (const float*)d_in[b + 4];
    B.t1  = (const float*)d_in[b + 5];
    B.t2  = (const float*)d_in[b + 6];
    B.t3  = (const float*)d_in[b + 7];
    B.t4  = (const float*)d_in[b + 8];
    B.Win = (const float*)d_in[b + 9];
    B.bin = (const float*)d_in[b + 10];
    B.Wout= (const float*)d_in[b + 11];
    B.bout= (const float*)d_in[b + 12];
    return B;
  };
  Branch SB = mk(1), CB = mk(14);
  const float* Ws2c = (const float*)d_in[27];
  const float* Wc2s = (const float*)d_in[28];
  const float* a1p  = (const float*)d_in[29];
  const float* a2p  = (const float*)d_in[30];
  const float* b2p  = (const float*)d_in[31];

  // workspace layout
  char* ws = (char*)d_ws;
  ushort* u    = (ushort*)(ws + 0);            // 2*50048*160*2 = 32,030,720
  ushort* h1   = (ushort*)(ws + 32030720);     // 2*50000*256*2 = 51,200,000
  ushort* V    = (ushort*)(ws + 83230720);     // 10000*512*2   = 10,240,000
  float*  M    = (float*) (ws + 93470720);     // 262,144
  ushort* Gt   = (ushort*)(ws + 93732864);     // 262,144
  float*  gvec = (float*) (ws + 93995008);     // 1,024
  ushort* Wt   = (ushort*)(ws + 93996032);     // 163,840
  int*   bfill = (int*)   (ws + 94159872);     // 1878*4 = 7,512 (pad to 7,680)
  unsigned* packed = (unsigned*)(ws + 94167552); // 1878*1280*4 = 9,615,360 (end ~103.8MB)

  hipMemsetAsync(bfill, 0, NBTOT * sizeof(int), stream);

  // weight folding (independent of graph work)
  build_wt2<<<512, KP, 0, stream>>>(SB.Win, CB.Win, SB.bin, CB.bin, Wt);
  build_small<<<128, 128, 0, stream>>>(Ws2c, Wc2s, a1p, a2p, b2p, M);
  build_G<<<512, 256, 0, stream>>>(SB.Wout, CB.Wout, M, Gt);
  build_gvec<<<1, 256, 0, stream>>>(SB.bout, CB.bout, M, gvec);

  // edge bucketing (block-local counting sort, batched append)
  bucketize_v3<<<2 * NCH0 + 2 * NCH1, 256, 0, stream>>>(
      SB.e0s, SB.e0d, CB.e0s, CB.e0d, SB.e1s, SB.e1d, CB.e1s, CB.e1d,
      bfill, packed);

  // compute pipeline
  agg0_fused<<<2 * NBK0, 256, 0, stream>>>(x,
      SB.t0, SB.t1, SB.t2, SB.t3, SB.t4,
      CB.t0, CB.t1, CB.t2, CB.t3, CB.t4,
      bfill, packed, u);
  gemm_mfma2<<<4 * GEMM_RB, 256, 0, stream>>>(u, Wt, h1);
  agg1_fused<<<2 * NBK1, 256, 0, stream>>>(h1, bfill, packed, V);
  tail_gemm<<<TAIL_NB, 64, 0, stream>>>(V, Gt, gvec, (float*)d_out);
}

// Round 9
// 456.235 us; speedup vs baseline: 1.2870x; 1.2870x over previous
//
#include <hip/hip_runtime.h>

// ---------------- problem constants ----------------
constexpr int cN0 = 200000, cN1 = 50000, cN2 = 10000;
constexpr int cE0 = 800000, cE1 = 160000;
constexpr int GD  = 144;       // 32+16+16+16+64
constexpr int KP  = 160;       // padded K for MFMA (col 144 = bias-multiplier lane)
constexpr int HID = 256, OUTD = 128;
constexpr int KT  = 512;       // tail K = 2*HID

// layer-0 buckets: 256 dsts each; layer-1 buckets: 64 dsts each
constexpr int WN0  = 256, CAP0 = 4608;      // lambda=4082, +8 sigma
constexpr int WN1  = 64,  CAP1 = 1280;      // lambda~1019, +8 sigma
constexpr int NBA0 = (cN1 + WN0 - 1) / WN0;   // 196 buckets/branch (L0)
constexpr int NBA1 = (cN2 + WN1 - 1) / WN1;   // 157 buckets/branch (L1)
constexpr int NFILL = 2 * NBA0 + 2 * NBA1;    // 706
constexpr size_t L1PBASE = (size_t)(2 * NBA0) * CAP0;   // packed offset of L1 region

constexpr int GEMM_RB = (50048 + 255) / 256; // 196 row-blocks
constexpr int TAIL_NB = cN2 / 16;            // 625
constexpr size_t UPLANE = (size_t)50048 * KP;

constexpr int CHUNK = 8192;                      // edges per bucketize block
constexpr int NCH0  = (cE0 + CHUNK - 1) / CHUNK; // 98
constexpr int NCH1  = (cE1 + CHUNK - 1) / CHUNK; // 20

typedef __attribute__((ext_vector_type(8))) short bf16x8;
typedef __attribute__((ext_vector_type(4))) float f32x4;

__device__ __forceinline__ ushort f2bf(float f) {
  union { float f; unsigned u; } v; v.f = f;
  unsigned r = (v.u + 0x7FFFu + ((v.u >> 16) & 1u)) >> 16;
  return (ushort)r;
}
__device__ __forceinline__ float bf2f(ushort u) {
  union { unsigned u; float f; } v; v.u = ((unsigned)u) << 16;
  return v.f;
}

// ---------------- bucketize v4 ----------------
// packed word (UNSIGNED): bits 0..17 src (<2^18), bits 18..25 local dst.
// Single global read of src & dst; dst stashed in LDS as u16 between phases.
__global__ __launch_bounds__(512)
void bucketize_v4(const int* __restrict__ s0, const int* __restrict__ d0,
                  const int* __restrict__ s1, const int* __restrict__ d1,
                  const int* __restrict__ s2, const int* __restrict__ d2,
                  const int* __restrict__ s3, const int* __restrict__ d3,
                  int* __restrict__ bfill, unsigned* __restrict__ packed) {
  __shared__ ushort rawD[CHUNK];                  // 16 KB
  __shared__ unsigned sed[CHUNK];                 // 32 KB sorted edges
  __shared__ int lcnt[NBA0], lstart[NBA0], lfill[NBA0];
  int bid = blockIdx.x, tid = threadIdx.x;
  const int *sp, *dp; int E, blk, NB, shift, wmask, CAPs, fbase;
  unsigned* pb;
  if (bid < NCH0) {
    sp = s0; dp = d0; E = cE0; blk = bid;             NB = NBA0; shift = 8; wmask = 255;
    CAPs = CAP0; fbase = 0;        pb = packed;
  } else if (bid < 2 * NCH0) {
    sp = s1; dp = d1; E = cE0; blk = bid - NCH0;      NB = NBA0; shift = 8; wmask = 255;
    CAPs = CAP0; fbase = NBA0;     pb = packed + (size_t)NBA0 * CAP0;
  } else if (bid < 2 * NCH0 + NCH1) {
    sp = s2; dp = d2; E = cE1; blk = bid - 2 * NCH0;  NB = NBA1; shift = 6; wmask = 63;
    CAPs = CAP1; fbase = 2 * NBA0; pb = packed + L1PBASE;
  } else {
    sp = s3; dp = d3; E = cE1; blk = bid - 2 * NCH0 - NCH1; NB = NBA1; shift = 6; wmask = 63;
    CAPs = CAP1; fbase = 2 * NBA0 + NBA1; pb = packed + L1PBASE + (size_t)NBA1 * CAP1;
  }
  int base = blk * CHUNK;
  int n = min(CHUNK, E - base);

  for (int i = tid; i < NB; i += 512) { lcnt[i] = 0; lfill[i] = 0; }
  __syncthreads();
  // phase 1: read dst once, stash u16, count buckets
  for (int i = tid; i < n; i += 512) {
    int dd = dp[base + i];
    rawD[i] = (ushort)dd;
    atomicAdd(&lcnt[dd >> shift], 1);
  }
  __syncthreads();
  // phase 2: single-wave exclusive scan (64 lanes x 4 bins = 256 >= NB)
  if (tid < 64) {
    int lane = tid;
    int i0 = lane * 4;
    int v[4], s = 0;
    #pragma unroll
    for (int j = 0; j < 4; ++j) {
      v[j] = (i0 + j < NB) ? lcnt[i0 + j] : 0;
      s += v[j];
    }
    int tot = s;
    #pragma unroll
    for (int off = 1; off < 64; off <<= 1) {
      int t = __shfl_up(s, off);
      if (lane >= off) s += t;
    }
    int excl = s - tot;
    #pragma unroll
    for (int j = 0; j < 4; ++j) {
      if (i0 + j < NB) lstart[i0 + j] = excl;
      excl += v[j];
    }
  }
  __syncthreads();
  // phase 3: read src once, scatter packed word into LDS bucket order
  for (int i = tid; i < n; i += 512) {
    int dd = rawD[i];
    int b = dd >> shift;
    int p = atomicAdd(&lfill[b], 1);
    sed[lstart[b] + p] = (unsigned)sp[base + i] | ((unsigned)(dd & wmask) << 18);
  }
  __syncthreads();
  // phase 4: one global atomic per (block,bucket); contiguous run copy-out
  int lane = tid & 63, wv = tid >> 6;
  for (int b = wv; b < NB; b += 8) {
    int cnt = lcnt[b];
    if (cnt == 0) continue;
    int gb0;
    if (lane == 0) gb0 = atomicAdd(&bfill[fbase + b], cnt);
    gb0 = __shfl(gb0, 0);
    int st = lstart[b];
    for (int i = lane; i < cnt; i += 64) {
      int gp = gb0 + i;
      if (gp < CAPs) pb[(size_t)b * CAPs + gp] = sed[st + i];
    }
  }
}

// ---------------- fused layer-0: 256-bin LDS sort + embedding mean-agg ------
__global__ __launch_bounds__(256)
void agg0_fused(const int* __restrict__ x,
                const float* __restrict__ s_t0, const float* __restrict__ s_t1,
                const float* __restrict__ s_t2, const float* __restrict__ s_t3,
                const float* __restrict__ s_t4,
                const float* __restrict__ c_t0, const float* __restrict__ c_t1,
                const float* __restrict__ c_t2, const float* __restrict__ c_t3,
                const float* __restrict__ c_t4,
                const int* __restrict__ bfill, const unsigned* __restrict__ packed,
                ushort* __restrict__ u) {
  __shared__ int lsrc[CAP0];
  __shared__ int lcnt[WN0], lstart[WN0], lfill[WN0];
  __shared__ int xst[4][64 * 5];
  int tid = threadIdx.x, w = tid >> 6, lane = tid & 63;
  int br = blockIdx.x / NBA0;
  int bk = blockIdx.x - br * NBA0;
  int gb = blockIdx.x;               // 0..391
  int dst0 = bk * WN0;
  int nd = min(WN0, cN1 - dst0);

  const float* t0 = br ? c_t0 : s_t0;
  const float* t1 = br ? c_t1 : s_t1;
  const float* t2 = br ? c_t2 : s_t2;
  const float* t3 = br ? c_t3 : s_t3;
  const float* t4 = br ? c_t4 : s_t4;
  const float* gbase; int gxs, gstride;
  if (lane < 8)       { gbase = t0 + lane * 4;        gxs = 0; gstride = 32; }
  else if (lane < 12) { gbase = t1 + (lane - 8) * 4;  gxs = 1; gstride = 16; }
  else if (lane < 16) { gbase = t2 + (lane - 12) * 4; gxs = 2; gstride = 16; }
  else if (lane < 20) { gbase = t3 + (lane - 16) * 4; gxs = 3; gstride = 16; }
  else if (lane < 36) { gbase = t4 + (lane - 20) * 4; gxs = 4; gstride = 64; }
  else                { gbase = t0;                   gxs = 0; gstride = 0;  }

  for (int i = tid; i < WN0; i += 256) { lcnt[i] = 0; lfill[i] = 0; }
  __syncthreads();
  int ec = min(bfill[gb], CAP0);
  const unsigned* pb = packed + (size_t)gb * CAP0;
  // pass A: count per-dst
  for (int i = tid; i < ec; i += 256)
    atomicAdd(&lcnt[pb[i] >> 18], 1);
  __syncthreads();
  // scan 256 bins (64 lanes x 4)
  if (tid < 64) {
    int i0 = tid * 4;
    int v[4], s = 0;
    #pragma unroll
    for (int j = 0; j < 4; ++j) { v[j] = lcnt[i0 + j]; s += v[j]; }
    int tot = s;
    #pragma unroll
    for (int off = 1; off < 64; off <<= 1) {
      int t = __shfl_up(s, off);
      if (lane >= off) s += t;
    }
    int excl = s - tot;
    #pragma unroll
    for (int j = 0; j < 4; ++j) { lstart[i0 + j] = excl; excl += v[j]; }
  }
  __syncthreads();
  // pass B: scatter src by dst (packed re-read, L2-hot)
  for (int i = tid; i < ec; i += 256) {
    unsigned v = pb[i];
    int l = (int)(v >> 18);
    int p = atomicAdd(&lfill[l], 1);
    lsrc[lstart[l] + p] = (int)(v & 0x3FFFFu);
  }
  __syncthreads();

  int* xstw = xst[w];
  for (int d = w; d < nd; d += 4) {
    int deg = lcnt[d], beg = lstart[d];
    float4 acc = make_float4(0.f, 0.f, 0.f, 0.f);
    for (int off = 0; off < deg; off += 64) {
      int nn = min(64, deg - off);
      if (lane < nn) {
        int s = lsrc[beg + off + lane];
        const int* xp = x + (size_t)s * 5;
        int v0 = xp[0], v1 = xp[1], v2 = xp[2], v3 = xp[3], v4 = xp[4];
        int* q = xstw + lane * 5;
        q[0] = v0; q[1] = v1; q[2] = v2; q[3] = v3; q[4] = v4;
      }
      int e = 0;
      for (; e + 8 <= nn; e += 8) {
        int rr[8];
        #pragma unroll
        for (int q = 0; q < 8; ++q) rr[q] = xstw[(e + q) * 5 + gxs];
        float4 g[8];
        #pragma unroll
        for (int q = 0; q < 8; ++q)
          g[q] = *reinterpret_cast<const float4*>(gbase + (size_t)rr[q] * gstride);
        #pragma unroll
        for (int q = 0; q < 8; ++q) {
          acc.x += g[q].x; acc.y += g[q].y; acc.z += g[q].z; acc.w += g[q].w;
        }
      }
      for (; e < nn; ++e) {
        int r = xstw[e * 5 + gxs];
        const float4 g = *reinterpret_cast<const float4*>(gbase + (size_t)r * gstride);
        acc.x += g.x; acc.y += g.y; acc.z += g.z; acc.w += g.w;
      }
    }
    float invc = (deg > 0) ? 1.f / (float)deg : 0.f;
    int dg = dst0 + d;
    ushort* ur = u + (size_t)br * UPLANE + (size_t)dg * KP;
    if (lane < 36) {
      const int* xd = x + (size_t)dg * 5;
      const float4 sv = *reinterpret_cast<const float4*>(gbase + (size_t)xd[gxs] * gstride);
      float4 r;
      r.x = sv.x + acc.x * invc;
      r.y = sv.y + acc.y * invc;
      r.z = sv.z + acc.z * invc;
      r.w = sv.w + acc.w * invc;
      ushort4 o;
      o.x = f2bf(r.x); o.y = f2bf(r.y); o.z = f2bf(r.z); o.w = f2bf(r.w);
      *reinterpret_cast<ushort4*>(ur + lane * 4) = o;
    } else if (lane == 36) {
      ushort4 o;
      o.x = f2bf(deg > 0 ? 2.f : 1.f);   // bias multiplier feature (col 144)
      o.y = 0; o.z = 0; o.w = 0;
      *reinterpret_cast<ushort4*>(ur + 144) = o;
    } else if (lane < 40) {
      *reinterpret_cast<ushort4*>(ur + lane * 4) = make_ushort4(0, 0, 0, 0);
    }
  }
}

// ---------------- W_in transpose+bf16+pad (+bias in row 144) ----------------
__global__ __launch_bounds__(KP)
void build_wt2(const float* __restrict__ Ws, const float* __restrict__ Wc,
               const float* __restrict__ bs, const float* __restrict__ bc,
               ushort* __restrict__ Wt) {
  int br = blockIdx.x >> 8, n = blockIdx.x & 255, k = threadIdx.x;
  const float* W = br ? Wc : Ws;
  const float* b = br ? bc : bs;
  float v = (k < GD) ? W[(size_t)k * HID + n] : ((k == GD) ? b[n] : 0.f);
  Wt[(size_t)br * HID * KP + n * KP + k] = f2bf(v);
}

// ---------------- layer-0 MFMA GEMM: h1 = relu(u@Wt^T), bf16 out -----------
__global__ __launch_bounds__(256)
void gemm_mfma2(const ushort* __restrict__ U, const ushort* __restrict__ Wt,
                ushort* __restrict__ h1) {
  __shared__ ushort Wth[128][KP + 8];
  int bid = blockIdx.x, tid = threadIdx.x;
  int rowblk = bid % GEMM_RB;
  int half = (bid / GEMM_RB) & 1;
  int br = bid / (2 * GEMM_RB);
  const ushort* Wsrc = Wt + ((size_t)br * HID + half * 128) * KP;
  for (int i = tid; i < 128 * (KP / 8); i += 256) {
    int r = i / (KP / 8), g = i - r * (KP / 8);
    *reinterpret_cast<bf16x8*>(&Wth[r][g * 8]) =
        *reinterpret_cast<const bf16x8*>(Wsrc + (size_t)r * KP + g * 8);
  }
  __syncthreads();
  int w = tid >> 6, lane = tid & 63, l15 = lane & 15, lhi = lane >> 4;
  int rowbase = rowblk * 256 + w * 64;
  const ushort* Ubr = U + (size_t)br * UPLANE;
  f32x4 acc[4][8];
  #pragma unroll
  for (int rt = 0; rt < 4; ++rt)
    #pragma unroll
    for (int ct = 0; ct < 8; ++ct) acc[rt][ct] = (f32x4){0.f, 0.f, 0.f, 0.f};
  #pragma unroll
  for (int ks = 0; ks < 5; ++ks) {
    bf16x8 bfr[8];
    #pragma unroll
    for (int ct = 0; ct < 8; ++ct)
      bfr[ct] = *reinterpret_cast<const bf16x8*>(&Wth[ct * 16 + l15][lhi * 8 + ks * 32]);
    #pragma unroll
    for (int rt = 0; rt < 4; ++rt) {
      int ar = rowbase + rt * 16 + l15;
      if (ar > 50047) ar = 50047;
      bf16x8 af = *reinterpret_cast<const bf16x8*>(Ubr + (size_t)ar * KP + lhi * 8 + ks * 32);
      #pragma unroll
      for (int ct = 0; ct < 8; ++ct)
        acc[rt][ct] = __builtin_amdgcn_mfma_f32_16x16x32_bf16(af, bfr[ct], acc[rt][ct], 0, 0, 0);
    }
  }
  ushort* h1p = h1 + (size_t)br * cN1 * HID + half * 128;
  #pragma unroll
  for (int rt = 0; rt < 4; ++rt) {
    #pragma unroll
    for (int r = 0; r < 4; ++r) {
      int row = rowbase + rt * 16 + lhi * 4 + r;
      if (row >= cN1) continue;
      #pragma unroll
      for (int ct = 0; ct < 8; ++ct)
        h1p[(size_t)row * HID + ct * 16 + l15] = f2bf(fmaxf(acc[rt][ct][r], 0.f));
    }
  }
}

// ---------------- fused layer-1: LDS sort + h1 mean-agg -> V bf16 ----------
__global__ __launch_bounds__(256)
void agg1_fused(const ushort* __restrict__ h1, const int* __restrict__ bfill,
                const unsigned* __restrict__ packed, ushort* __restrict__ V) {
  __shared__ unsigned lvals[CAP1];
  __shared__ int lsrc[CAP1];
  __shared__ int lcnt[WN1], lstart[WN1], lfill[WN1];
  int tid = threadIdx.x, w = tid >> 6, lane = tid & 63;
  int br = blockIdx.x / NBA1;
  int bk = blockIdx.x - br * NBA1;
  int fb = 2 * NBA0 + blockIdx.x;
  int dst0 = bk * WN1;
  int nd = min(WN1, cN2 - dst0);
  const ushort* h1p = h1 + (size_t)br * cN1 * HID;

  if (tid < WN1) { lcnt[tid] = 0; lfill[tid] = 0; }
  __syncthreads();
  int ec = min(bfill[fb], CAP1);
  const unsigned* pb = packed + L1PBASE + (size_t)blockIdx.x * CAP1;
  for (int i = tid; i < ec; i += 256) {
    unsigned v = pb[i];
    lvals[i] = v;
    atomicAdd(&lcnt[v >> 18], 1);
  }
  __syncthreads();
  if (tid < 64) {
    int c = lcnt[tid]; int s = c;
    #pragma unroll
    for (int off = 1; off < 64; off <<= 1) {
      int t = __shfl_up(s, off);
      if (lane >= off) s += t;
    }
    lstart[tid] = s - c;
  }
  __syncthreads();
  for (int i = tid; i < ec; i += 256) {
    unsigned v = lvals[i];
    int l = (int)(v >> 18);
    int p = atomicAdd(&lfill[l], 1);
    lsrc[lstart[l] + p] = (int)(v & 0x3FFFFu);
  }
  __syncthreads();

  for (int d = w; d < nd; d += 4) {
    int deg = lcnt[d], beg = lstart[d];
    float4 acc = make_float4(0.f, 0.f, 0.f, 0.f);
    int e = 0;
    for (; e + 4 <= deg; e += 4) {
      int sA = lsrc[beg + e], sB = lsrc[beg + e + 1];
      int sC = lsrc[beg + e + 2], sD = lsrc[beg + e + 3];
      ushort4 hA = *reinterpret_cast<const ushort4*>(h1p + (size_t)sA * HID + lane * 4);
      ushort4 hB = *reinterpret_cast<const ushort4*>(h1p + (size_t)sB * HID + lane * 4);
      ushort4 hC = *reinterpret_cast<const ushort4*>(h1p + (size_t)sC * HID + lane * 4);
      ushort4 hD = *reinterpret_cast<const ushort4*>(h1p + (size_t)sD * HID + lane * 4);
      acc.x += bf2f(hA.x) + bf2f(hB.x) + bf2f(hC.x) + bf2f(hD.x);
      acc.y += bf2f(hA.y) + bf2f(hB.y) + bf2f(hC.y) + bf2f(hD.y);
      acc.z += bf2f(hA.z) + bf2f(hB.z) + bf2f(hC.z) + bf2f(hD.z);
      acc.w += bf2f(hA.w) + bf2f(hB.w) + bf2f(hC.w) + bf2f(hD.w);
    }
    for (; e < deg; ++e) {
      int s = lsrc[beg + e];
      ushort4 hv = *reinterpret_cast<const ushort4*>(h1p + (size_t)s * HID + lane * 4);
      acc.x += bf2f(hv.x); acc.y += bf2f(hv.y); acc.z += bf2f(hv.z); acc.w += bf2f(hv.w);
    }
    float invc = (deg > 0) ? 1.f / (float)deg : 0.f;
    int dg = dst0 + d;
    ushort4 dv = *reinterpret_cast<const ushort4*>(h1p + (size_t)dg * HID + lane * 4);
    ushort4 o;
    o.x = f2bf(bf2f(dv.x) + acc.x * invc);
    o.y = f2bf(bf2f(dv.y) + acc.y * invc);
    o.z = f2bf(bf2f(dv.z) + acc.z * invc);
    o.w = f2bf(bf2f(dv.w) + acc.w * invc);
    *reinterpret_cast<ushort4*>(V + (size_t)dg * KT + br * HID + lane * 4) = o;
  }
}

// ---------------- integration weight folding ----------------
__global__ __launch_bounds__(128)
void build_small(const float* __restrict__ Ws2c, const float* __restrict__ Wc2s,
                 const float* __restrict__ a1p, const float* __restrict__ a2p,
                 const float* __restrict__ b2p, float* __restrict__ M) {
  int r = blockIdx.x, c = threadIdx.x;
  float A1 = a1p[0], A2 = a2p[0], B2 = b2p[0];
  float c0 = 1.f - A2 - B2;
  float c1 = A2 + B2 * (1.f - A1);
  float c2 = A1 * B2;
  float s1 = 0.f, s4 = 0.f;
  for (int k = 0; k < 128; ++k) {
    s1 += Ws2c[r * 128 + k] * Wc2s[k * 128 + c];
    s4 += Wc2s[r * 128 + k] * Ws2c[k * 128 + c];
  }
  float eye = (r == c) ? c0 : 0.f;
  M[0 * 16384 + r * 128 + c] = c2 * s1 + eye;
  M[1 * 16384 + r * 128 + c] = c1 * Wc2s[r * 128 + c];
  M[2 * 16384 + r * 128 + c] = c1 * Ws2c[r * 128 + c];
  M[3 * 16384 + r * 128 + c] = c2 * s4 + eye;
}

__global__ __launch_bounds__(256)
void build_G(const float* __restrict__ Wout_s, const float* __restrict__ Wout_c,
             const float* __restrict__ M, ushort* __restrict__ Gt) {
  __shared__ float wr[128];
  int k = blockIdx.x, j = threadIdx.x;
  const float* wrow = (k < 256) ? &Wout_s[(size_t)k * 128] : &Wout_c[(size_t)(k - 256) * 128];
  if (j < 128) wr[j] = wrow[j];
  __syncthreads();
  const float* Mm = (j < 128) ? (k < 256 ? M : M + 16384)
                              : (k < 256 ? M + 2 * 16384 : M + 3 * 16384);
  int jj = j & 127;
  float s = 0.f;
  for (int t = 0; t < 128; ++t) s += wr[t] * Mm[t * 128 + jj];
  Gt[(size_t)j * KT + k] = f2bf(s);
}

__global__ __launch_bounds__(256)
void build_gvec(const float* __restrict__ b_s, const float* __restrict__ b_c,
                const float* __restrict__ M, float* __restrict__ gvec) {
  int j = threadIdx.x, jj = j & 127;
  const float* Ma = (j < 128) ? M : M + 2 * 16384;
  const float* Mb = (j < 128) ? M + 16384 : M + 3 * 16384;
  float s = 0.f;
  for (int t = 0; t < 128; ++t)
    s += b_s[t] * Ma[t * 128 + jj] + b_c[t] * Mb[t * 128 + jj];
  gvec[j] = s;
}

// ---------------- tail MFMA GEMM: out = V @ Gt^T + gvec ----------------
__global__ __launch_bounds__(64)
void tail_gemm(const ushort* __restrict__ V, const ushort* __restrict__ Gt,
               const float* __restrict__ gvec, float* __restrict__ out) {
  int lane = threadIdx.x;
  int l15 = lane & 15, lhi = lane >> 4;
  int rowW = blockIdx.x * 16;
  f32x4 acc[16];
  #pragma unroll
  for (int t = 0; t < 16; ++t) acc[t] = (f32x4){0.f, 0.f, 0.f, 0.f};
  const ushort* vp = V + (size_t)(rowW + l15) * KT + lhi * 8;
  const ushort* gp = Gt + (size_t)l15 * KT + lhi * 8;
  #pragma unroll
  for (int ks = 0; ks < 16; ++ks) {
    bf16x8 a = *reinterpret_cast<const bf16x8*>(vp + ks * 32);
    #pragma unroll
    for (int t = 0; t < 16; ++t) {
      bf16x8 b = *reinterpret_cast<const bf16x8*>(gp + (size_t)t * 16 * KT + ks * 32);
      acc[t] = __builtin_amdgcn_mfma_f32_16x16x32_bf16(a, b, acc[t], 0, 0, 0);
    }
  }
  int r0 = rowW + lhi * 4;
  #pragma unroll
  for (int t = 0; t < 16; ++t) {
    int col = t * 16 + l15;
    float gv = gvec[col];
    float* dst = (col < 128) ? out + (size_t)r0 * OUTD + col
                             : out + (size_t)cN2 * OUTD + (size_t)r0 * OUTD + (col - 128);
    #pragma unroll
    for (int r = 0; r < 4; ++r)
      dst[(size_t)r * OUTD] = acc[t][r] + gv;
  }
}

// ---------------- launch ----------------
extern "C" void kernel_launch(void* const* d_in, const int* in_sizes, int n_in,
                              void* d_out, int out_size, void* d_ws, size_t ws_size,
                              hipStream_t stream) {
  const int* x = (const int*)d_in[0];
  struct Branch {
    const int *e0s, *e0d, *e1s, *e1d;
    const float *t0, *t1, *t2, *t3, *t4, *Win, *bin, *Wout, *bout;
  };
  auto mk = [&](int b) {
    Branch B;
    B.e0s = (const int*)d_in[b + 0];
    B.e0d = (const int*)d_in[b + 1];
    B.e1s = (const int*)d_in[b + 2];
    B.e1d = (const int*)d_in[b + 3];
    B.t0  = (const float*)d_in[b + 4];
    B.t1  = (const float*)d_in[b + 5];
    B.t2  = (const float*)d_in[b + 6];
    B.t3  = (const float*)d_in[b + 7];
    B.t4  = (const float*)d_in[b + 8];
    B.Win = (const float*)d_in[b + 9];
    B.bin = (const float*)d_in[b + 10];
    B.Wout= (const float*)d_in[b + 11];
    B.bout= (const float*)d_in[b + 12];
    return B;
  };
  Branch SB = mk(1), CB = mk(14);
  const float* Ws2c = (const float*)d_in[27];
  const float* Wc2s = (const float*)d_in[28];
  const float* a1p  = (const float*)d_in[29];
  const float* a2p  = (const float*)d_in[30];
  const float* b2p  = (const float*)d_in[31];

  // workspace layout
  char* ws = (char*)d_ws;
  ushort* u    = (ushort*)(ws + 0);            // 2*50048*160*2 = 32,030,720
  ushort* h1   = (ushort*)(ws + 32030720);     // 2*50000*256*2 = 51,200,000
  ushort* V    = (ushort*)(ws + 83230720);     // 10000*512*2   = 10,240,000
  float*  M    = (float*) (ws + 93470720);     // 262,144
  ushort* Gt   = (ushort*)(ws + 93732864);     // 262,144
  float*  gvec = (float*) (ws + 93995008);     // 1,024
  ushort* Wt   = (ushort*)(ws + 93996032);     // 163,840
  int*   bfill = (int*)   (ws + 94159872);     // 706*4 = 2,824 (pad to 7,680)
  unsigned* packed = (unsigned*)(ws + 94167552); // 392*4608*4 + 314*1280*4 = 8,833,024

  hipMemsetAsync(bfill, 0, NFILL * sizeof(int), stream);

  // weight folding (independent of graph work)
  build_wt2<<<512, KP, 0, stream>>>(SB.Win, CB.Win, SB.bin, CB.bin, Wt);
  build_small<<<128, 128, 0, stream>>>(Ws2c, Wc2s, a1p, a2p, b2p, M);
  build_G<<<512, 256, 0, stream>>>(SB.Wout, CB.Wout, M, Gt);
  build_gvec<<<1, 256, 0, stream>>>(SB.bout, CB.bout, M, gvec);

  // edge bucketing
  bucketize_v4<<<2 * NCH0 + 2 * NCH1, 512, 0, stream>>>(
      SB.e0s, SB.e0d, CB.e0s, CB.e0d, SB.e1s, SB.e1d, CB.e1s, CB.e1d,
      bfill, packed);

  // compute pipeline
  agg0_fused<<<2 * NBA0, 256, 0, stream>>>(x,
      SB.t0, SB.t1, SB.t2, SB.t3, SB.t4,
      CB.t0, CB.t1, CB.t2, CB.t3, CB.t4,
      bfill, packed, u);
  gemm_mfma2<<<4 * GEMM_RB, 256, 0, stream>>>(u, Wt, h1);
  agg1_fused<<<2 * NBA1, 256, 0, stream>>>(h1, bfill, packed, V);
  tail_gemm<<<TAIL_NB, 64, 0, stream>>>(V, Gt, gvec, (float*)d_out);
}

// Round 10
// 391.791 us; speedup vs baseline: 1.4986x; 1.1645x over previous
//
#include <hip/hip_runtime.h>

// ---------------- problem constants ----------------
constexpr int cN0 = 200000, cN1 = 50000, cN2 = 10000;
constexpr int cE0 = 800000, cE1 = 160000;
constexpr int GD  = 144;       // 32+16+16+16+64
constexpr int KP  = 160;       // padded K for MFMA (col 144 = bias-multiplier lane)
constexpr int HID = 256, OUTD = 128;
constexpr int KT  = 512;       // tail K = 2*HID

// layer-0 buckets: 256 dsts each; layer-1 buckets: 64 dsts each
constexpr int WN0  = 256, CAP0 = 4608;      // lambda=4082, +8 sigma
constexpr int WN1  = 64,  CAP1 = 1280;      // lambda~1019, +8 sigma
constexpr int NBA0 = (cN1 + WN0 - 1) / WN0;   // 196 buckets/branch (L0)
constexpr int NBA1 = (cN2 + WN1 - 1) / WN1;   // 157 buckets/branch (L1)
constexpr int NFILL = 2 * NBA0 + 2 * NBA1;    // 706
constexpr size_t L1PBASE = (size_t)(2 * NBA0) * CAP0;   // packed offset of L1 region

constexpr int GEMM_RB = (50048 + 255) / 256; // 196 row-blocks
constexpr int TAIL_NB = cN2 / 16;            // 625
constexpr size_t UPLANE = (size_t)50048 * KP;

constexpr int CHUNK = 8192;                      // edges per bucketize block
constexpr int NCH0  = (cE0 + CHUNK - 1) / CHUNK; // 98
constexpr int NCH1  = (cE1 + CHUNK - 1) / CHUNK; // 20

typedef __attribute__((ext_vector_type(8))) short bf16x8;
typedef __attribute__((ext_vector_type(4))) float f32x4;

__device__ __forceinline__ ushort f2bf(float f) {
  union { float f; unsigned u; } v; v.f = f;
  unsigned r = (v.u + 0x7FFFu + ((v.u >> 16) & 1u)) >> 16;
  return (ushort)r;
}
__device__ __forceinline__ float bf2f(ushort u) {
  union { unsigned u; float f; } v; v.u = ((unsigned)u) << 16;
  return v.f;
}

// ---------------- bucketize v4 (unchanged from R8) ----------------
// packed word (UNSIGNED): bits 0..17 src (<2^18), bits 18..25 local dst.
__global__ __launch_bounds__(512)
void bucketize_v4(const int* __restrict__ s0, const int* __restrict__ d0,
                  const int* __restrict__ s1, const int* __restrict__ d1,
                  const int* __restrict__ s2, const int* __restrict__ d2,
                  const int* __restrict__ s3, const int* __restrict__ d3,
                  int* __restrict__ bfill, unsigned* __restrict__ packed) {
  __shared__ ushort rawD[CHUNK];                  // 16 KB
  __shared__ unsigned sed[CHUNK];                 // 32 KB sorted edges
  __shared__ int lcnt[NBA0], lstart[NBA0], lfill[NBA0];
  int bid = blockIdx.x, tid = threadIdx.x;
  const int *sp, *dp; int E, blk, NB, shift, wmask, CAPs, fbase;
  unsigned* pb;
  if (bid < NCH0) {
    sp = s0; dp = d0; E = cE0; blk = bid;             NB = NBA0; shift = 8; wmask = 255;
    CAPs = CAP0; fbase = 0;        pb = packed;
  } else if (bid < 2 * NCH0) {
    sp = s1; dp = d1; E = cE0; blk = bid - NCH0;      NB = NBA0; shift = 8; wmask = 255;
    CAPs = CAP0; fbase = NBA0;     pb = packed + (size_t)NBA0 * CAP0;
  } else if (bid < 2 * NCH0 + NCH1) {
    sp = s2; dp = d2; E = cE1; blk = bid - 2 * NCH0;  NB = NBA1; shift = 6; wmask = 63;
    CAPs = CAP1; fbase = 2 * NBA0; pb = packed + L1PBASE;
  } else {
    sp = s3; dp = d3; E = cE1; blk = bid - 2 * NCH0 - NCH1; NB = NBA1; shift = 6; wmask = 63;
    CAPs = CAP1; fbase = 2 * NBA0 + NBA1; pb = packed + L1PBASE + (size_t)NBA1 * CAP1;
  }
  int base = blk * CHUNK;
  int n = min(CHUNK, E - base);

  for (int i = tid; i < NB; i += 512) { lcnt[i] = 0; lfill[i] = 0; }
  __syncthreads();
  for (int i = tid; i < n; i += 512) {
    int dd = dp[base + i];
    rawD[i] = (ushort)dd;
    atomicAdd(&lcnt[dd >> shift], 1);
  }
  __syncthreads();
  if (tid < 64) {
    int lane = tid;
    int i0 = lane * 4;
    int v[4], s = 0;
    #pragma unroll
    for (int j = 0; j < 4; ++j) {
      v[j] = (i0 + j < NB) ? lcnt[i0 + j] : 0;
      s += v[j];
    }
    int tot = s;
    #pragma unroll
    for (int off = 1; off < 64; off <<= 1) {
      int t = __shfl_up(s, off);
      if (lane >= off) s += t;
    }
    int excl = s - tot;
    #pragma unroll
    for (int j = 0; j < 4; ++j) {
      if (i0 + j < NB) lstart[i0 + j] = excl;
      excl += v[j];
    }
  }
  __syncthreads();
  for (int i = tid; i < n; i += 512) {
    int dd = rawD[i];
    int b = dd >> shift;
    int p = atomicAdd(&lfill[b], 1);
    sed[lstart[b] + p] = (unsigned)sp[base + i] | ((unsigned)(dd & wmask) << 18);
  }
  __syncthreads();
  int lane = tid & 63, wv = tid >> 6;
  for (int b = wv; b < NB; b += 8) {
    int cnt = lcnt[b];
    if (cnt == 0) continue;
    int gb0;
    if (lane == 0) gb0 = atomicAdd(&bfill[fbase + b], cnt);
    gb0 = __shfl(gb0, 0);
    int st = lstart[b];
    for (int i = lane; i < cnt; i += 64) {
      int gp = gb0 + i;
      if (gp < CAPs) pb[(size_t)b * CAPs + gp] = sed[st + i];
    }
  }
}

// ---------------- fused layer-0: 16-wave block, 256-bin sort + mean-agg ----
__global__ __launch_bounds__(1024)
void agg0_fused(const int* __restrict__ x,
                const float* __restrict__ s_t0, const float* __restrict__ s_t1,
                const float* __restrict__ s_t2, const float* __restrict__ s_t3,
                const float* __restrict__ s_t4,
                const float* __restrict__ c_t0, const float* __restrict__ c_t1,
                const float* __restrict__ c_t2, const float* __restrict__ c_t3,
                const float* __restrict__ c_t4,
                const int* __restrict__ bfill, const unsigned* __restrict__ packed,
                ushort* __restrict__ u) {
  __shared__ int lsrc[CAP0];                 // 18.4 KB
  __shared__ int lcnt[WN0], lstart[WN0], lfill[WN0];  // 3 KB
  __shared__ int xst[16][64 * 5];            // 20 KB
  int tid = threadIdx.x, w = tid >> 6, lane = tid & 63;
  int br = blockIdx.x / NBA0;
  int bk = blockIdx.x - br * NBA0;
  int gb = blockIdx.x;               // 0..391
  int dst0 = bk * WN0;
  int nd = min(WN0, cN1 - dst0);

  const float* t0 = br ? c_t0 : s_t0;
  const float* t1 = br ? c_t1 : s_t1;
  const float* t2 = br ? c_t2 : s_t2;
  const float* t3 = br ? c_t3 : s_t3;
  const float* t4 = br ? c_t4 : s_t4;
  const float* gbase; int gxs, gstride;
  if (lane < 8)       { gbase = t0 + lane * 4;        gxs = 0; gstride = 32; }
  else if (lane < 12) { gbase = t1 + (lane - 8) * 4;  gxs = 1; gstride = 16; }
  else if (lane < 16) { gbase = t2 + (lane - 12) * 4; gxs = 2; gstride = 16; }
  else if (lane < 20) { gbase = t3 + (lane - 16) * 4; gxs = 3; gstride = 16; }
  else if (lane < 36) { gbase = t4 + (lane - 20) * 4; gxs = 4; gstride = 64; }
  else                { gbase = t0;                   gxs = 0; gstride = 0;  }

  for (int i = tid; i < WN0; i += 1024) { lcnt[i] = 0; lfill[i] = 0; }
  __syncthreads();
  int ec = min(bfill[gb], CAP0);
  const unsigned* pb = packed + (size_t)gb * CAP0;
  // pass A: count per-dst
  for (int i = tid; i < ec; i += 1024)
    atomicAdd(&lcnt[pb[i] >> 18], 1);
  __syncthreads();
  // scan 256 bins (single wave: 64 lanes x 4)
  if (tid < 64) {
    int i0 = tid * 4;
    int v[4], s = 0;
    #pragma unroll
    for (int j = 0; j < 4; ++j) { v[j] = lcnt[i0 + j]; s += v[j]; }
    int tot = s;
    #pragma unroll
    for (int off = 1; off < 64; off <<= 1) {
      int t = __shfl_up(s, off);
      if (lane >= off) s += t;
    }
    int excl = s - tot;
    #pragma unroll
    for (int j = 0; j < 4; ++j) { lstart[i0 + j] = excl; excl += v[j]; }
  }
  __syncthreads();
  // pass B: scatter src by dst (packed re-read, L2-hot)
  for (int i = tid; i < ec; i += 1024) {
    unsigned v = pb[i];
    int l = (int)(v >> 18);
    int p = atomicAdd(&lfill[l], 1);
    lsrc[lstart[l] + p] = (int)(v & 0x3FFFFu);
  }
  __syncthreads();

  int* xstw = xst[w];
  for (int d = w; d < nd; d += 16) {
    int deg = lcnt[d], beg = lstart[d];
    float4 acc = make_float4(0.f, 0.f, 0.f, 0.f);
    for (int off = 0; off < deg; off += 64) {
      int nn = min(64, deg - off);
      if (lane < nn) {
        int s = lsrc[beg + off + lane];
        const int* xp = x + (size_t)s * 5;
        int v0 = xp[0], v1 = xp[1], v2 = xp[2], v3 = xp[3], v4 = xp[4];
        int* q = xstw + lane * 5;
        q[0] = v0; q[1] = v1; q[2] = v2; q[3] = v3; q[4] = v4;
      }
      int e = 0;
      for (; e + 8 <= nn; e += 8) {
        int rr[8];
        #pragma unroll
        for (int q = 0; q < 8; ++q) rr[q] = xstw[(e + q) * 5 + gxs];
        float4 g[8];
        #pragma unroll
        for (int q = 0; q < 8; ++q)
          g[q] = *reinterpret_cast<const float4*>(gbase + (size_t)rr[q] * gstride);
        #pragma unroll
        for (int q = 0; q < 8; ++q) {
          acc.x += g[q].x; acc.y += g[q].y; acc.z += g[q].z; acc.w += g[q].w;
        }
      }
      for (; e < nn; ++e) {
        int r = xstw[e * 5 + gxs];
        const float4 g = *reinterpret_cast<const float4*>(gbase + (size_t)r * gstride);
        acc.x += g.x; acc.y += g.y; acc.z += g.z; acc.w += g.w;
      }
    }
    float invc = (deg > 0) ? 1.f / (float)deg : 0.f;
    int dg = dst0 + d;
    ushort* ur = u + (size_t)br * UPLANE + (size_t)dg * KP;
    if (lane < 36) {
      const int* xd = x + (size_t)dg * 5;
      const float4 sv = *reinterpret_cast<const float4*>(gbase + (size_t)xd[gxs] * gstride);
      float4 r;
      r.x = sv.x + acc.x * invc;
      r.y = sv.y + acc.y * invc;
      r.z = sv.z + acc.z * invc;
      r.w = sv.w + acc.w * invc;
      ushort4 o;
      o.x = f2bf(r.x); o.y = f2bf(r.y); o.z = f2bf(r.z); o.w = f2bf(r.w);
      *reinterpret_cast<ushort4*>(ur + lane * 4) = o;
    } else if (lane == 36) {
      ushort4 o;
      o.x = f2bf(deg > 0 ? 2.f : 1.f);   // bias multiplier feature (col 144)
      o.y = 0; o.z = 0; o.w = 0;
      *reinterpret_cast<ushort4*>(ur + 144) = o;
    } else if (lane < 40) {
      *reinterpret_cast<ushort4*>(ur + lane * 4) = make_ushort4(0, 0, 0, 0);
    }
  }
}

// ---------------- W_in transpose+bf16+pad (+bias in row 144) ----------------
__global__ __launch_bounds__(KP)
void build_wt2(const float* __restrict__ Ws, const float* __restrict__ Wc,
               const float* __restrict__ bs, const float* __restrict__ bc,
               ushort* __restrict__ Wt) {
  int br = blockIdx.x >> 8, n = blockIdx.x & 255, k = threadIdx.x;
  const float* W = br ? Wc : Ws;
  const float* b = br ? bc : bs;
  float v = (k < GD) ? W[(size_t)k * HID + n] : ((k == GD) ? b[n] : 0.f);
  Wt[(size_t)br * HID * KP + n * KP + k] = f2bf(v);
}

// ---------------- layer-0 MFMA GEMM: h1 = relu(u@Wt^T), bf16 out -----------
__global__ __launch_bounds__(256)
void gemm_mfma2(const ushort* __restrict__ U, const ushort* __restrict__ Wt,
                ushort* __restrict__ h1) {
  __shared__ ushort Wth[128][KP + 8];
  int bid = blockIdx.x, tid = threadIdx.x;
  int rowblk = bid % GEMM_RB;
  int half = (bid / GEMM_RB) & 1;
  int br = bid / (2 * GEMM_RB);
  const ushort* Wsrc = Wt + ((size_t)br * HID + half * 128) * KP;
  for (int i = tid; i < 128 * (KP / 8); i += 256) {
    int r = i / (KP / 8), g = i - r * (KP / 8);
    *reinterpret_cast<bf16x8*>(&Wth[r][g * 8]) =
        *reinterpret_cast<const bf16x8*>(Wsrc + (size_t)r * KP + g * 8);
  }
  __syncthreads();
  int w = tid >> 6, lane = tid & 63, l15 = lane & 15, lhi = lane >> 4;
  int rowbase = rowblk * 256 + w * 64;
  const ushort* Ubr = U + (size_t)br * UPLANE;
  f32x4 acc[4][8];
  #pragma unroll
  for (int rt = 0; rt < 4; ++rt)
    #pragma unroll
    for (int ct = 0; ct < 8; ++ct) acc[rt][ct] = (f32x4){0.f, 0.f, 0.f, 0.f};
  #pragma unroll
  for (int ks = 0; ks < 5; ++ks) {
    bf16x8 bfr[8];
    #pragma unroll
    for (int ct = 0; ct < 8; ++ct)
      bfr[ct] = *reinterpret_cast<const bf16x8*>(&Wth[ct * 16 + l15][lhi * 8 + ks * 32]);
    #pragma unroll
    for (int rt = 0; rt < 4; ++rt) {
      int ar = rowbase + rt * 16 + l15;
      if (ar > 50047) ar = 50047;
      bf16x8 af = *reinterpret_cast<const bf16x8*>(Ubr + (size_t)ar * KP + lhi * 8 + ks * 32);
      #pragma unroll
      for (int ct = 0; ct < 8; ++ct)
        acc[rt][ct] = __builtin_amdgcn_mfma_f32_16x16x32_bf16(af, bfr[ct], acc[rt][ct], 0, 0, 0);
    }
  }
  ushort* h1p = h1 + (size_t)br * cN1 * HID + half * 128;
  #pragma unroll
  for (int rt = 0; rt < 4; ++rt) {
    #pragma unroll
    for (int r = 0; r < 4; ++r) {
      int row = rowbase + rt * 16 + lhi * 4 + r;
      if (row >= cN1) continue;
      #pragma unroll
      for (int ct = 0; ct < 8; ++ct)
        h1p[(size_t)row * HID + ct * 16 + l15] = f2bf(fmaxf(acc[rt][ct][r], 0.f));
    }
  }
}

// ---------------- fused layer-1: LDS sort + h1 mean-agg -> V bf16 ----------
__global__ __launch_bounds__(256)
void agg1_fused(const ushort* __restrict__ h1, const int* __restrict__ bfill,
                const unsigned* __restrict__ packed, ushort* __restrict__ V) {
  __shared__ unsigned lvals[CAP1];
  __shared__ int lsrc[CAP1];
  __shared__ int lcnt[WN1], lstart[WN1], lfill[WN1];
  int tid = threadIdx.x, w = tid >> 6, lane = tid & 63;
  int br = blockIdx.x / NBA1;
  int bk = blockIdx.x - br * NBA1;
  int fb = 2 * NBA0 + blockIdx.x;
  int dst0 = bk * WN1;
  int nd = min(WN1, cN2 - dst0);
  const ushort* h1p = h1 + (size_t)br * cN1 * HID;

  if (tid < WN1) { lcnt[tid] = 0; lfill[tid] = 0; }
  __syncthreads();
  int ec = min(bfill[fb], CAP1);
  const unsigned* pb = packed + L1PBASE + (size_t)blockIdx.x * CAP1;
  for (int i = tid; i < ec; i += 256) {
    unsigned v = pb[i];
    lvals[i] = v;
    atomicAdd(&lcnt[v >> 18], 1);
  }
  __syncthreads();
  if (tid < 64) {
    int c = lcnt[tid]; int s = c;
    #pragma unroll
    for (int off = 1; off < 64; off <<= 1) {
      int t = __shfl_up(s, off);
      if (lane >= off) s += t;
    }
    lstart[tid] = s - c;
  }
  __syncthreads();
  for (int i = tid; i < ec; i += 256) {
    unsigned v = lvals[i];
    int l = (int)(v >> 18);
    int p = atomicAdd(&lfill[l], 1);
    lsrc[lstart[l] + p] = (int)(v & 0x3FFFFu);
  }
  __syncthreads();

  for (int d = w; d < nd; d += 4) {
    int deg = lcnt[d], beg = lstart[d];
    float4 acc = make_float4(0.f, 0.f, 0.f, 0.f);
    int e = 0;
    for (; e + 4 <= deg; e += 4) {
      int sA = lsrc[beg + e], sB = lsrc[beg + e + 1];
      int sC = lsrc[beg + e + 2], sD = lsrc[beg + e + 3];
      ushort4 hA = *reinterpret_cast<const ushort4*>(h1p + (size_t)sA * HID + lane * 4);
      ushort4 hB = *reinterpret_cast<const ushort4*>(h1p + (size_t)sB * HID + lane * 4);
      ushort4 hC = *reinterpret_cast<const ushort4*>(h1p + (size_t)sC * HID + lane * 4);
      ushort4 hD = *reinterpret_cast<const ushort4*>(h1p + (size_t)sD * HID + lane * 4);
      acc.x += bf2f(hA.x) + bf2f(hB.x) + bf2f(hC.x) + bf2f(hD.x);
      acc.y += bf2f(hA.y) + bf2f(hB.y) + bf2f(hC.y) + bf2f(hD.y);
      acc.z += bf2f(hA.z) + bf2f(hB.z) + bf2f(hC.z) + bf2f(hD.z);
      acc.w += bf2f(hA.w) + bf2f(hB.w) + bf2f(hC.w) + bf2f(hD.w);
    }
    for (; e < deg; ++e) {
      int s = lsrc[beg + e];
      ushort4 hv = *reinterpret_cast<const ushort4*>(h1p + (size_t)s * HID + lane * 4);
      acc.x += bf2f(hv.x); acc.y += bf2f(hv.y); acc.z += bf2f(hv.z); acc.w += bf2f(hv.w);
    }
    float invc = (deg > 0) ? 1.f / (float)deg : 0.f;
    int dg = dst0 + d;
    ushort4 dv = *reinterpret_cast<const ushort4*>(h1p + (size_t)dg * HID + lane * 4);
    ushort4 o;
    o.x = f2bf(bf2f(dv.x) + acc.x * invc);
    o.y = f2bf(bf2f(dv.y) + acc.y * invc);
    o.z = f2bf(bf2f(dv.z) + acc.z * invc);
    o.w = f2bf(bf2f(dv.w) + acc.w * invc);
    *reinterpret_cast<ushort4*>(V + (size_t)dg * KT + br * HID + lane * 4) = o;
  }
}

// ---------------- integration weight folding ----------------
__global__ __launch_bounds__(128)
void build_small(const float* __restrict__ Ws2c, const float* __restrict__ Wc2s,
                 const float* __restrict__ a1p, const float* __restrict__ a2p,
                 const float* __restrict__ b2p, float* __restrict__ M) {
  int r = blockIdx.x, c = threadIdx.x;
  float A1 = a1p[0], A2 = a2p[0], B2 = b2p[0];
  float c0 = 1.f - A2 - B2;
  float c1 = A2 + B2 * (1.f - A1);
  float c2 = A1 * B2;
  float s1 = 0.f, s4 = 0.f;
  for (int k = 0; k < 128; ++k) {
    s1 += Ws2c[r * 128 + k] * Wc2s[k * 128 + c];
    s4 += Wc2s[r * 128 + k] * Ws2c[k * 128 + c];
  }
  float eye = (r == c) ? c0 : 0.f;
  M[0 * 16384 + r * 128 + c] = c2 * s1 + eye;
  M[1 * 16384 + r * 128 + c] = c1 * Wc2s[r * 128 + c];
  M[2 * 16384 + r * 128 + c] = c1 * Ws2c[r * 128 + c];
  M[3 * 16384 + r * 128 + c] = c2 * s4 + eye;
}

__global__ __launch_bounds__(256)
void build_G(const float* __restrict__ Wout_s, const float* __restrict__ Wout_c,
             const float* __restrict__ M, ushort* __restrict__ Gt) {
  __shared__ float wr[128];
  int k = blockIdx.x, j = threadIdx.x;
  const float* wrow = (k < 256) ? &Wout_s[(size_t)k * 128] : &Wout_c[(size_t)(k - 256) * 128];
  if (j < 128) wr[j] = wrow[j];
  __syncthreads();
  const float* Mm = (j < 128) ? (k < 256 ? M : M + 16384)
                              : (k < 256 ? M + 2 * 16384 : M + 3 * 16384);
  int jj = j & 127;
  float s = 0.f;
  for (int t = 0; t < 128; ++t) s += wr[t] * Mm[t * 128 + jj];
  Gt[(size_t)j * KT + k] = f2bf(s);
}

__global__ __launch_bounds__(256)
void build_gvec(const float* __restrict__ b_s, const float* __restrict__ b_c,
                const float* __restrict__ M, float* __restrict__ gvec) {
  int j = threadIdx.x, jj = j & 127;
  const float* Ma = (j < 128) ? M : M + 2 * 16384;
  const float* Mb = (j < 128) ? M + 16384 : M + 3 * 16384;
  float s = 0.f;
  for (int t = 0; t < 128; ++t)
    s += b_s[t] * Ma[t * 128 + jj] + b_c[t] * Mb[t * 128 + jj];
  gvec[j] = s;
}

// ---------------- tail MFMA GEMM: out = V @ Gt^T + gvec ----------------
__global__ __launch_bounds__(64)
void tail_gemm(const ushort* __restrict__ V, const ushort* __restrict__ Gt,
               const float* __restrict__ gvec, float* __restrict__ out) {
  int lane = threadIdx.x;
  int l15 = lane & 15, lhi = lane >> 4;
  int rowW = blockIdx.x * 16;
  f32x4 acc[16];
  #pragma unroll
  for (int t = 0; t < 16; ++t) acc[t] = (f32x4){0.f, 0.f, 0.f, 0.f};
  const ushort* vp = V + (size_t)(rowW + l15) * KT + lhi * 8;
  const ushort* gp = Gt + (size_t)l15 * KT + lhi * 8;
  #pragma unroll
  for (int ks = 0; ks < 16; ++ks) {
    bf16x8 a = *reinterpret_cast<const bf16x8*>(vp + ks * 32);
    #pragma unroll
    for (int t = 0; t < 16; ++t) {
      bf16x8 b = *reinterpret_cast<const bf16x8*>(gp + (size_t)t * 16 * KT + ks * 32);
      acc[t] = __builtin_amdgcn_mfma_f32_16x16x32_bf16(a, b, acc[t], 0, 0, 0);
    }
  }
  int r0 = rowW + lhi * 4;
  #pragma unroll
  for (int t = 0; t < 16; ++t) {
    int col = t * 16 + l15;
    float gv = gvec[col];
    float* dst = (col < 128) ? out + (size_t)r0 * OUTD + col
                             : out + (size_t)cN2 * OUTD + (size_t)r0 * OUTD + (col - 128);
    #pragma unroll
    for (int r = 0; r < 4; ++r)
      dst[(size_t)r * OUTD] = acc[t][r] + gv;
  }
}

// ---------------- launch ----------------
extern "C" void kernel_launch(void* const* d_in, const int* in_sizes, int n_in,
                              void* d_out, int out_size, void* d_ws, size_t ws_size,
                              hipStream_t stream) {
  const int* x = (const int*)d_in[0];
  struct Branch {
    const int *e0s, *e0d, *e1s, *e1d;
    const float *t0, *t1, *t2, *t3, *t4, *Win, *bin, *Wout, *bout;
  };
  auto mk = [&](int b) {
    Branch B;
    B.e0s = (const int*)d_in[b + 0];
    B.e0d = (const int*)d_in[b + 1];
    B.e1s = (const int*)d_in[b + 2];
    B.e1d = (const int*)d_in[b + 3];
    B.t0  = (const float*)d_in[b + 4];
    B.t1  = (const float*)d_in[b + 5];
    B.t2  = (const float*)d_in[b + 6];
    B.t3  = (const float*)d_in[b + 7];
    B.t4  = (const float*)d_in[b + 8];
    B.Win = (const float*)d_in[b + 9];
    B.bin = (const float*)d_in[b + 10];
    B.Wout= (const float*)d_in[b + 11];
    B.bout= (const float*)d_in[b + 12];
    return B;
  };
  Branch SB = mk(1), CB = mk(14);
  const float* Ws2c = (const float*)d_in[27];
  const float* Wc2s = (const float*)d_in[28];
  const float* a1p  = (const float*)d_in[29];
  const float* a2p  = (const float*)d_in[30];
  const float* b2p  = (const float*)d_in[31];

  // workspace layout
  char* ws = (char*)d_ws;
  ushort* u    = (ushort*)(ws + 0);            // 2*50048*160*2 = 32,030,720
  ushort* h1   = (ushort*)(ws + 32030720);     // 2*50000*256*2 = 51,200,000
  ushort* V    = (ushort*)(ws + 83230720);     // 10000*512*2   = 10,240,000
  float*  M    = (float*) (ws + 93470720);     // 262,144
  ushort* Gt   = (ushort*)(ws + 93732864);     // 262,144
  float*  gvec = (float*) (ws + 93995008);     // 1,024
  ushort* Wt   = (ushort*)(ws + 93996032);     // 163,840
  int*   bfill = (int*)   (ws + 94159872);     // 706*4 = 2,824 (pad to 7,680)
  unsigned* packed = (unsigned*)(ws + 94167552); // 392*4608*4 + 314*1280*4 = 8,833,024

  hipMemsetAsync(bfill, 0, NFILL * sizeof(int), stream);

  // weight folding (independent of graph work)
  build_wt2<<<512, KP, 0, stream>>>(SB.Win, CB.Win, SB.bin, CB.bin, Wt);
  build_small<<<128, 128, 0, stream>>>(Ws2c, Wc2s, a1p, a2p, b2p, M);
  build_G<<<512, 256, 0, stream>>>(SB.Wout, CB.Wout, M, Gt);
  build_gvec<<<1, 256, 0, stream>>>(SB.bout, CB.bout, M, gvec);

  // edge bucketing
  bucketize_v4<<<2 * NCH0 + 2 * NCH1, 512, 0, stream>>>(
      SB.e0s, SB.e0d, CB.e0s, CB.e0d, SB.e1s, SB.e1d, CB.e1s, CB.e1d,
      bfill, packed);

  // compute pipeline
  agg0_fused<<<2 * NBA0, 1024, 0, stream>>>(x,
      SB.t0, SB.t1, SB.t2, SB.t3, SB.t4,
      CB.t0, CB.t1, CB.t2, CB.t3, CB.t4,
      bfill, packed, u);
  gemm_mfma2<<<4 * GEMM_RB, 256, 0, stream>>>(u, Wt, h1);
  agg1_fused<<<2 * NBA1, 256, 0, stream>>>(h1, bfill, packed, V);
  tail_gemm<<<TAIL_NB, 64, 0, stream>>>(V, Gt, gvec, (float*)d_out);
}

// Round 11
// 375.902 us; speedup vs baseline: 1.5620x; 1.0423x over previous
//
#include <hip/hip_runtime.h>

// ---------------- problem constants ----------------
constexpr int cN0 = 200000, cN1 = 50000, cN2 = 10000;
constexpr int cE0 = 800000, cE1 = 160000;
constexpr int GD  = 144;       // 32+16+16+16+64
constexpr int KP  = 160;       // padded K for MFMA (col 144 = bias-multiplier lane)
constexpr int HID = 256, OUTD = 128;
constexpr int KT  = 512;       // tail K = 2*HID

// layer-0 buckets: 256 dsts each; layer-1 buckets: 64 dsts each
constexpr int WN0  = 256, CAP0 = 4608;      // lambda=4082, +8 sigma
constexpr int WN1  = 64,  CAP1 = 1280;      // lambda~1019, +8 sigma
constexpr int CAP0H = 2560;                 // half-bucket capacity (lambda=2041)
constexpr int NBA0 = (cN1 + WN0 - 1) / WN0;   // 196 buckets/branch (L0)
constexpr int NBA1 = (cN2 + WN1 - 1) / WN1;   // 157 buckets/branch (L1)
constexpr int NFILL = 2 * NBA0 + 2 * NBA1;    // 706
constexpr size_t L1PBASE = (size_t)(2 * NBA0) * CAP0;   // packed offset of L1 region

constexpr int GEMM_RB = (50048 + 255) / 256; // 196 row-blocks
constexpr int TAIL_NB = cN2 / 16;            // 625
constexpr size_t UPLANE = (size_t)50048 * KP;

constexpr int CHUNK = 8192;                      // edges per bucketize block
constexpr int NCH0  = (cE0 + CHUNK - 1) / CHUNK; // 98
constexpr int NCH1  = (cE1 + CHUNK - 1) / CHUNK; // 20

typedef __attribute__((ext_vector_type(8))) short bf16x8;
typedef __attribute__((ext_vector_type(4))) float f32x4;
typedef unsigned long long u64;

__device__ __forceinline__ ushort f2bf(float f) {
  union { float f; unsigned u; } v; v.f = f;
  unsigned r = (v.u + 0x7FFFu + ((v.u >> 16) & 1u)) >> 16;
  return (ushort)r;
}
__device__ __forceinline__ float bf2f(ushort u) {
  union { unsigned u; float f; } v; v.u = ((unsigned)u) << 16;
  return v.f;
}

// ---------------- pack x rows into u64 (5 x 10-bit fields) ----------------
__global__ __launch_bounds__(256)
void pack_x(const int* __restrict__ x, u64* __restrict__ px) {
  int i = blockIdx.x * 256 + threadIdx.x;
  if (i < cN0) {
    const int* xp = x + (size_t)i * 5;
    u64 v = (u64)(xp[0] & 1023)
          | ((u64)(xp[1] & 1023) << 10)
          | ((u64)(xp[2] & 1023) << 20)
          | ((u64)(xp[3] & 1023) << 30)
          | ((u64)(xp[4] & 1023) << 40);
    px[i] = v;
  }
}

// ---------------- bucketize v4 (unchanged) ----------------
// packed word (UNSIGNED): bits 0..17 src (<2^18), bits 18..25 local dst.
__global__ __launch_bounds__(512)
void bucketize_v4(const int* __restrict__ s0, const int* __restrict__ d0,
                  const int* __restrict__ s1, const int* __restrict__ d1,
                  const int* __restrict__ s2, const int* __restrict__ d2,
                  const int* __restrict__ s3, const int* __restrict__ d3,
                  int* __restrict__ bfill, unsigned* __restrict__ packed) {
  __shared__ ushort rawD[CHUNK];                  // 16 KB
  __shared__ unsigned sed[CHUNK];                 // 32 KB sorted edges
  __shared__ int lcnt[NBA0], lstart[NBA0], lfill[NBA0];
  int bid = blockIdx.x, tid = threadIdx.x;
  const int *sp, *dp; int E, blk, NB, shift, wmask, CAPs, fbase;
  unsigned* pb;
  if (bid < NCH0) {
    sp = s0; dp = d0; E = cE0; blk = bid;             NB = NBA0; shift = 8; wmask = 255;
    CAPs = CAP0; fbase = 0;        pb = packed;
  } else if (bid < 2 * NCH0) {
    sp = s1; dp = d1; E = cE0; blk = bid - NCH0;      NB = NBA0; shift = 8; wmask = 255;
    CAPs = CAP0; fbase = NBA0;     pb = packed + (size_t)NBA0 * CAP0;
  } else if (bid < 2 * NCH0 + NCH1) {
    sp = s2; dp = d2; E = cE1; blk = bid - 2 * NCH0;  NB = NBA1; shift = 6; wmask = 63;
    CAPs = CAP1; fbase = 2 * NBA0; pb = packed + L1PBASE;
  } else {
    sp = s3; dp = d3; E = cE1; blk = bid - 2 * NCH0 - NCH1; NB = NBA1; shift = 6; wmask = 63;
    CAPs = CAP1; fbase = 2 * NBA0 + NBA1; pb = packed + L1PBASE + (size_t)NBA1 * CAP1;
  }
  int base = blk * CHUNK;
  int n = min(CHUNK, E - base);

  for (int i = tid; i < NB; i += 512) { lcnt[i] = 0; lfill[i] = 0; }
  __syncthreads();
  for (int i = tid; i < n; i += 512) {
    int dd = dp[base + i];
    rawD[i] = (ushort)dd;
    atomicAdd(&lcnt[dd >> shift], 1);
  }
  __syncthreads();
  if (tid < 64) {
    int lane = tid;
    int i0 = lane * 4;
    int v[4], s = 0;
    #pragma unroll
    for (int j = 0; j < 4; ++j) {
      v[j] = (i0 + j < NB) ? lcnt[i0 + j] : 0;
      s += v[j];
    }
    int tot = s;
    #pragma unroll
    for (int off = 1; off < 64; off <<= 1) {
      int t = __shfl_up(s, off);
      if (lane >= off) s += t;
    }
    int excl = s - tot;
    #pragma unroll
    for (int j = 0; j < 4; ++j) {
      if (i0 + j < NB) lstart[i0 + j] = excl;
      excl += v[j];
    }
  }
  __syncthreads();
  for (int i = tid; i < n; i += 512) {
    int dd = rawD[i];
    int b = dd >> shift;
    int p = atomicAdd(&lfill[b], 1);
    sed[lstart[b] + p] = (unsigned)sp[base + i] | ((unsigned)(dd & wmask) << 18);
  }
  __syncthreads();
  int lane = tid & 63, wv = tid >> 6;
  for (int b = wv; b < NB; b += 8) {
    int cnt = lcnt[b];
    if (cnt == 0) continue;
    int gb0;
    if (lane == 0) gb0 = atomicAdd(&bfill[fbase + b], cnt);
    gb0 = __shfl(gb0, 0);
    int st = lstart[b];
    for (int i = lane; i < cnt; i += 64) {
      int gp = gb0 + i;
      if (gp < CAPs) pb[(size_t)b * CAPs + gp] = sed[st + i];
    }
  }
}

// ---------------- fused layer-0: half-bucket blocks, packed-x staging ------
// grid: (br*NBA0 + bk)*2 + h ; block = 512 threads (8 waves), 128 dsts.
__global__ __launch_bounds__(512)
void agg0_fused(const u64* __restrict__ px,
                const float* __restrict__ s_t0, const float* __restrict__ s_t1,
                const float* __restrict__ s_t2, const float* __restrict__ s_t3,
                const float* __restrict__ s_t4,
                const float* __restrict__ c_t0, const float* __restrict__ c_t1,
                const float* __restrict__ c_t2, const float* __restrict__ c_t3,
                const float* __restrict__ c_t4,
                const int* __restrict__ bfill, const unsigned* __restrict__ packed,
                ushort* __restrict__ u) {
  __shared__ int lsrc[CAP0H];                       // 10 KB
  __shared__ int lcnt[128], lstart[128], lfill[128]; // 1.5 KB
  __shared__ u64 pxst[8][64];                        // 4 KB
  int tid = threadIdx.x, w = tid >> 6, lane = tid & 63;
  int gb = blockIdx.x >> 1;
  int h  = blockIdx.x & 1;
  int br = gb / NBA0;
  int bk = gb - br * NBA0;
  int dst0 = bk * WN0 + h * 128;
  int nd = min(128, cN1 - dst0);
  if (nd <= 0) return;

  const float* t0 = br ? c_t0 : s_t0;
  const float* t1 = br ? c_t1 : s_t1;
  const float* t2 = br ? c_t2 : s_t2;
  const float* t3 = br ? c_t3 : s_t3;
  const float* t4 = br ? c_t4 : s_t4;
  const float* gbase; int sh, gstride;
  bool has = (lane < 36);
  if (lane < 8)       { gbase = t0 + lane * 4;        sh = 0;  gstride = 32; }
  else if (lane < 12) { gbase = t1 + (lane - 8) * 4;  sh = 10; gstride = 16; }
  else if (lane < 16) { gbase = t2 + (lane - 12) * 4; sh = 20; gstride = 16; }
  else if (lane < 20) { gbase = t3 + (lane - 16) * 4; sh = 30; gstride = 16; }
  else if (lane < 36) { gbase = t4 + (lane - 20) * 4; sh = 40; gstride = 64; }
  else                { gbase = t0;                   sh = 0;  gstride = 0;  }

  for (int i = tid; i < 128; i += 512) { lcnt[i] = 0; lfill[i] = 0; }
  __syncthreads();
  int ec = min(bfill[gb], CAP0);
  const unsigned* pb = packed + (size_t)gb * CAP0;
  // pass A: count per-dst (own half only)
  for (int i = tid; i < ec; i += 512) {
    unsigned v = pb[i];
    if (((v >> 25) & 1u) == (unsigned)h)
      atomicAdd(&lcnt[(v >> 18) & 127u], 1);
  }
  __syncthreads();
  // scan 128 bins (single wave: 64 lanes x 2)
  if (tid < 64) {
    int i0 = tid * 2;
    int v0 = lcnt[i0], v1 = lcnt[i0 + 1];
    int s = v0 + v1, tot = s;
    #pragma unroll
    for (int off = 1; off < 64; off <<= 1) {
      int t = __shfl_up(s, off);
      if (lane >= off) s += t;
    }
    int excl = s - tot;
    lstart[i0] = excl;
    lstart[i0 + 1] = excl + v0;
  }
  __syncthreads();
  // pass B: scatter src by dst (own half only)
  for (int i = tid; i < ec; i += 512) {
    unsigned v = pb[i];
    if (((v >> 25) & 1u) == (unsigned)h) {
      int l = (int)((v >> 18) & 127u);
      int p = atomicAdd(&lfill[l], 1);
      int idx = lstart[l] + p;
      if (idx < CAP0H) lsrc[idx] = (int)(v & 0x3FFFFu);
    }
  }
  __syncthreads();

  u64* pxw = pxst[w];
  for (int d = w; d < nd; d += 8) {
    int deg = lcnt[d], beg = lstart[d];
    float4 acc = make_float4(0.f, 0.f, 0.f, 0.f);
    for (int off = 0; off < deg; off += 64) {
      int nn = min(64, deg - off);
      if (lane < nn)
        pxw[lane] = px[lsrc[beg + off + lane]];
      int e = 0;
      for (; e + 8 <= nn; e += 8) {
        int rr[8];
        #pragma unroll
        for (int q = 0; q < 8; ++q)
          rr[q] = (int)((pxw[e + q] >> sh) & 1023ull);
        float4 g[8];
        #pragma unroll
        for (int q = 0; q < 8; ++q)
          g[q] = has ? *reinterpret_cast<const float4*>(gbase + (size_t)rr[q] * gstride)
                     : make_float4(0.f, 0.f, 0.f, 0.f);
        #pragma unroll
        for (int q = 0; q < 8; ++q) {
          acc.x += g[q].x; acc.y += g[q].y; acc.z += g[q].z; acc.w += g[q].w;
        }
      }
      for (; e < nn; ++e) {
        int r = (int)((pxw[e] >> sh) & 1023ull);
        if (has) {
          const float4 g = *reinterpret_cast<const float4*>(gbase + (size_t)r * gstride);
          acc.x += g.x; acc.y += g.y; acc.z += g.z; acc.w += g.w;
        }
      }
    }
    float invc = (deg > 0) ? 1.f / (float)deg : 0.f;
    int dg = dst0 + d;
    ushort* ur = u + (size_t)br * UPLANE + (size_t)dg * KP;
    u64 pvd = px[dg];
    if (has) {
      int rowd = (int)((pvd >> sh) & 1023ull);
      const float4 sv = *reinterpret_cast<const float4*>(gbase + (size_t)rowd * gstride);
      float4 r;
      r.x = sv.x + acc.x * invc;
      r.y = sv.y + acc.y * invc;
      r.z = sv.z + acc.z * invc;
      r.w = sv.w + acc.w * invc;
      ushort4 o;
      o.x = f2bf(r.x); o.y = f2bf(r.y); o.z = f2bf(r.z); o.w = f2bf(r.w);
      *reinterpret_cast<ushort4*>(ur + lane * 4) = o;
    } else if (lane == 36) {
      ushort4 o;
      o.x = f2bf(deg > 0 ? 2.f : 1.f);   // bias multiplier feature (col 144)
      o.y = 0; o.z = 0; o.w = 0;
      *reinterpret_cast<ushort4*>(ur + 144) = o;
    } else if (lane < 40) {
      *reinterpret_cast<ushort4*>(ur + lane * 4) = make_ushort4(0, 0, 0, 0);
    }
  }
}

// ---------------- W_in transpose+bf16+pad (+bias in row 144) ----------------
__global__ __launch_bounds__(KP)
void build_wt2(const float* __restrict__ Ws, const float* __restrict__ Wc,
               const float* __restrict__ bs, const float* __restrict__ bc,
               ushort* __restrict__ Wt) {
  int br = blockIdx.x >> 8, n = blockIdx.x & 255, k = threadIdx.x;
  const float* W = br ? Wc : Ws;
  const float* b = br ? bc : bs;
  float v = (k < GD) ? W[(size_t)k * HID + n] : ((k == GD) ? b[n] : 0.f);
  Wt[(size_t)br * HID * KP + n * KP + k] = f2bf(v);
}

// ---------------- layer-0 MFMA GEMM: h1 = relu(u@Wt^T), bf16 out -----------
__global__ __launch_bounds__(256)
void gemm_mfma2(const ushort* __restrict__ U, const ushort* __restrict__ Wt,
                ushort* __restrict__ h1) {
  __shared__ ushort Wth[128][KP + 8];
  int bid = blockIdx.x, tid = threadIdx.x;
  int rowblk = bid % GEMM_RB;
  int half = (bid / GEMM_RB) & 1;
  int br = bid / (2 * GEMM_RB);
  const ushort* Wsrc = Wt + ((size_t)br * HID + half * 128) * KP;
  for (int i = tid; i < 128 * (KP / 8); i += 256) {
    int r = i / (KP / 8), g = i - r * (KP / 8);
    *reinterpret_cast<bf16x8*>(&Wth[r][g * 8]) =
        *reinterpret_cast<const bf16x8*>(Wsrc + (size_t)r * KP + g * 8);
  }
  __syncthreads();
  int w = tid >> 6, lane = tid & 63, l15 = lane & 15, lhi = lane >> 4;
  int rowbase = rowblk * 256 + w * 64;
  const ushort* Ubr = U + (size_t)br * UPLANE;
  f32x4 acc[4][8];
  #pragma unroll
  for (int rt = 0; rt < 4; ++rt)
    #pragma unroll
    for (int ct = 0; ct < 8; ++ct) acc[rt][ct] = (f32x4){0.f, 0.f, 0.f, 0.f};
  #pragma unroll
  for (int ks = 0; ks < 5; ++ks) {
    bf16x8 bfr[8];
    #pragma unroll
    for (int ct = 0; ct < 8; ++ct)
      bfr[ct] = *reinterpret_cast<const bf16x8*>(&Wth[ct * 16 + l15][lhi * 8 + ks * 32]);
    #pragma unroll
    for (int rt = 0; rt < 4; ++rt) {
      int ar = rowbase + rt * 16 + l15;
      if (ar > 50047) ar = 50047;
      bf16x8 af = *reinterpret_cast<const bf16x8*>(Ubr + (size_t)ar * KP + lhi * 8 + ks * 32);
      #pragma unroll
      for (int ct = 0; ct < 8; ++ct)
        acc[rt][ct] = __builtin_amdgcn_mfma_f32_16x16x32_bf16(af, bfr[ct], acc[rt][ct], 0, 0, 0);
    }
  }
  ushort* h1p = h1 + (size_t)br * cN1 * HID + half * 128;
  #pragma unroll
  for (int rt = 0; rt < 4; ++rt) {
    #pragma unroll
    for (int r = 0; r < 4; ++r) {
      int row = rowbase + rt * 16 + lhi * 4 + r;
      if (row >= cN1) continue;
      #pragma unroll
      for (int ct = 0; ct < 8; ++ct)
        h1p[(size_t)row * HID + ct * 16 + l15] = f2bf(fmaxf(acc[rt][ct][r], 0.f));
    }
  }
}

// ---------------- fused layer-1: LDS sort + h1 mean-agg -> V bf16 ----------
__global__ __launch_bounds__(256)
void agg1_fused(const ushort* __restrict__ h1, const int* __restrict__ bfill,
                const unsigned* __restrict__ packed, ushort* __restrict__ V) {
  __shared__ unsigned lvals[CAP1];
  __shared__ int lsrc[CAP1];
  __shared__ int lcnt[WN1], lstart[WN1], lfill[WN1];
  int tid = threadIdx.x, w = tid >> 6, lane = tid & 63;
  int br = blockIdx.x / NBA1;
  int bk = blockIdx.x - br * NBA1;
  int fb = 2 * NBA0 + blockIdx.x;
  int dst0 = bk * WN1;
  int nd = min(WN1, cN2 - dst0);
  const ushort* h1p = h1 + (size_t)br * cN1 * HID;

  if (tid < WN1) { lcnt[tid] = 0; lfill[tid] = 0; }
  __syncthreads();
  int ec = min(bfill[fb], CAP1);
  const unsigned* pb = packed + L1PBASE + (size_t)blockIdx.x * CAP1;
  for (int i = tid; i < ec; i += 256) {
    unsigned v = pb[i];
    lvals[i] = v;
    atomicAdd(&lcnt[v >> 18], 1);
  }
  __syncthreads();
  if (tid < 64) {
    int c = lcnt[tid]; int s = c;
    #pragma unroll
    for (int off = 1; off < 64; off <<= 1) {
      int t = __shfl_up(s, off);
      if (lane >= off) s += t;
    }
    lstart[tid] = s - c;
  }
  __syncthreads();
  for (int i = tid; i < ec; i += 256) {
    unsigned v = lvals[i];
    int l = (int)(v >> 18);
    int p = atomicAdd(&lfill[l], 1);
    lsrc[lstart[l] + p] = (int)(v & 0x3FFFFu);
  }
  __syncthreads();

  for (int d = w; d < nd; d += 4) {
    int deg = lcnt[d], beg = lstart[d];
    float4 acc = make_float4(0.f, 0.f, 0.f, 0.f);
    int e = 0;
    for (; e + 4 <= deg; e += 4) {
      int sA = lsrc[beg + e], sB = lsrc[beg + e + 1];
      int sC = lsrc[beg + e + 2], sD = lsrc[beg + e + 3];
      ushort4 hA = *reinterpret_cast<const ushort4*>(h1p + (size_t)sA * HID + lane * 4);
      ushort4 hB = *reinterpret_cast<const ushort4*>(h1p + (size_t)sB * HID + lane * 4);
      ushort4 hC = *reinterpret_cast<const ushort4*>(h1p + (size_t)sC * HID + lane * 4);
      ushort4 hD = *reinterpret_cast<const ushort4*>(h1p + (size_t)sD * HID + lane * 4);
      acc.x += bf2f(hA.x) + bf2f(hB.x) + bf2f(hC.x) + bf2f(hD.x);
      acc.y += bf2f(hA.y) + bf2f(hB.y) + bf2f(hC.y) + bf2f(hD.y);
      acc.z += bf2f(hA.z) + bf2f(hB.z) + bf2f(hC.z) + bf2f(hD.z);
      acc.w += bf2f(hA.w) + bf2f(hB.w) + bf2f(hC.w) + bf2f(hD.w);
    }
    for (; e < deg; ++e) {
      int s = lsrc[beg + e];
      ushort4 hv = *reinterpret_cast<const ushort4*>(h1p + (size_t)s * HID + lane * 4);
      acc.x += bf2f(hv.x); acc.y += bf2f(hv.y); acc.z += bf2f(hv.z); acc.w += bf2f(hv.w);
    }
    float invc = (deg > 0) ? 1.f / (float)deg : 0.f;
    int dg = dst0 + d;
    ushort4 dv = *reinterpret_cast<const ushort4*>(h1p + (size_t)dg * HID + lane * 4);
    ushort4 o;
    o.x = f2bf(bf2f(dv.x) + acc.x * invc);
    o.y = f2bf(bf2f(dv.y) + acc.y * invc);
    o.z = f2bf(bf2f(dv.z) + acc.z * invc);
    o.w = f2bf(bf2f(dv.w) + acc.w * invc);
    *reinterpret_cast<ushort4*>(V + (size_t)dg * KT + br * HID + lane * 4) = o;
  }
}

// ---------------- integration weight folding ----------------
__global__ __launch_bounds__(128)
void build_small(const float* __restrict__ Ws2c, const float* __restrict__ Wc2s,
                 const float* __restrict__ a1p, const float* __restrict__ a2p,
                 const float* __restrict__ b2p, float* __restrict__ M) {
  int r = blockIdx.x, c = threadIdx.x;
  float A1 = a1p[0], A2 = a2p[0], B2 = b2p[0];
  float c0 = 1.f - A2 - B2;
  float c1 = A2 + B2 * (1.f - A1);
  float c2 = A1 * B2;
  float s1 = 0.f, s4 = 0.f;
  for (int k = 0; k < 128; ++k) {
    s1 += Ws2c[r * 128 + k] * Wc2s[k * 128 + c];
    s4 += Wc2s[r * 128 + k] * Ws2c[k * 128 + c];
  }
  float eye = (r == c) ? c0 : 0.f;
  M[0 * 16384 + r * 128 + c] = c2 * s1 + eye;
  M[1 * 16384 + r * 128 + c] = c1 * Wc2s[r * 128 + c];
  M[2 * 16384 + r * 128 + c] = c1 * Ws2c[r * 128 + c];
  M[3 * 16384 + r * 128 + c] = c2 * s4 + eye;
}

__global__ __launch_bounds__(256)
void build_G(const float* __restrict__ Wout_s, const float* __restrict__ Wout_c,
             const float* __restrict__ M, ushort* __restrict__ Gt) {
  __shared__ float wr[128];
  int k = blockIdx.x, j = threadIdx.x;
  const float* wrow = (k < 256) ? &Wout_s[(size_t)k * 128] : &Wout_c[(size_t)(k - 256) * 128];
  if (j < 128) wr[j] = wrow[j];
  __syncthreads();
  const float* Mm = (j < 128) ? (k < 256 ? M : M + 16384)
                              : (k < 256 ? M + 2 * 16384 : M + 3 * 16384);
  int jj = j & 127;
  float s = 0.f;
  for (int t = 0; t < 128; ++t) s += wr[t] * Mm[t * 128 + jj];
  Gt[(size_t)j * KT + k] = f2bf(s);
}

__global__ __launch_bounds__(256)
void build_gvec(const float* __restrict__ b_s, const float* __restrict__ b_c,
                const float* __restrict__ M, float* __restrict__ gvec) {
  int j = threadIdx.x, jj = j & 127;
  const float* Ma = (j < 128) ? M : M + 2 * 16384;
  const float* Mb = (j < 128) ? M + 16384 : M + 3 * 16384;
  float s = 0.f;
  for (int t = 0; t < 128; ++t)
    s += b_s[t] * Ma[t * 128 + jj] + b_c[t] * Mb[t * 128 + jj];
  gvec[j] = s;
}

// ---------------- tail MFMA GEMM: out = V @ Gt^T + gvec ----------------
__global__ __launch_bounds__(64)
void tail_gemm(const ushort* __restrict__ V, const ushort* __restrict__ Gt,
               const float* __restrict__ gvec, float* __restrict__ out) {
  int lane = threadIdx.x;
  int l15 = lane & 15, lhi = lane >> 4;
  int rowW = blockIdx.x * 16;
  f32x4 acc[16];
  #pragma unroll
  for (int t = 0; t < 16; ++t) acc[t] = (f32x4){0.f, 0.f, 0.f, 0.f};
  const ushort* vp = V + (size_t)(rowW + l15) * KT + lhi * 8;
  const ushort* gp = Gt + (size_t)l15 * KT + lhi * 8;
  #pragma unroll
  for (int ks = 0; ks < 16; ++ks) {
    bf16x8 a = *reinterpret_cast<const bf16x8*>(vp + ks * 32);
    #pragma unroll
    for (int t = 0; t < 16; ++t) {
      bf16x8 b = *reinterpret_cast<const bf16x8*>(gp + (size_t)t * 16 * KT + ks * 32);
      acc[t] = __builtin_amdgcn_mfma_f32_16x16x32_bf16(a, b, acc[t], 0, 0, 0);
    }
  }
  int r0 = rowW + lhi * 4;
  #pragma unroll
  for (int t = 0; t < 16; ++t) {
    int col = t * 16 + l15;
    float gv = gvec[col];
    float* dst = (col < 128) ? out + (size_t)r0 * OUTD + col
                             : out + (size_t)cN2 * OUTD + (size_t)r0 * OUTD + (col - 128);
    #pragma unroll
    for (int r = 0; r < 4; ++r)
      dst[(size_t)r * OUTD] = acc[t][r] + gv;
  }
}

// ---------------- launch ----------------
extern "C" void kernel_launch(void* const* d_in, const int* in_sizes, int n_in,
                              void* d_out, int out_size, void* d_ws, size_t ws_size,
                              hipStream_t stream) {
  const int* x = (const int*)d_in[0];
  struct Branch {
    const int *e0s, *e0d, *e1s, *e1d;
    const float *t0, *t1, *t2, *t3, *t4, *Win, *bin, *Wout, *bout;
  };
  auto mk = [&](int b) {
    Branch B;
    B.e0s = (const int*)d_in[b + 0];
    B.e0d = (const int*)d_in[b + 1];
    B.e1s = (const int*)d_in[b + 2];
    B.e1d = (const int*)d_in[b + 3];
    B.t0  = (const float*)d_in[b + 4];
    B.t1  = (const float*)d_in[b + 5];
    B.t2  = (const float*)d_in[b + 6];
    B.t3  = (const float*)d_in[b + 7];
    B.t4  = (const float*)d_in[b + 8];
    B.Win = (const float*)d_in[b + 9];
    B.bin = (const float*)d_in[b + 10];
    B.Wout= (const float*)d_in[b + 11];
    B.bout= (const float*)d_in[b + 12];
    return B;
  };
  Branch SB = mk(1), CB = mk(14);
  const float* Ws2c = (const float*)d_in[27];
  const float* Wc2s = (const float*)d_in[28];
  const float* a1p  = (const float*)d_in[29];
  const float* a2p  = (const float*)d_in[30];
  const float* b2p  = (const float*)d_in[31];

  // workspace layout
  char* ws = (char*)d_ws;
  ushort* u    = (ushort*)(ws + 0);            // 2*50048*160*2 = 32,030,720
  ushort* h1   = (ushort*)(ws + 32030720);     // 2*50000*256*2 = 51,200,000
  ushort* V    = (ushort*)(ws + 83230720);     // 10000*512*2   = 10,240,000
  float*  M    = (float*) (ws + 93470720);     // 262,144
  ushort* Gt   = (ushort*)(ws + 93732864);     // 262,144
  float*  gvec = (float*) (ws + 93995008);     // 1,024
  ushort* Wt   = (ushort*)(ws + 93996032);     // 163,840
  int*   bfill = (int*)   (ws + 94159872);     // 706*4 (pad to 7,680)
  unsigned* packed = (unsigned*)(ws + 94167552); // 8,833,024
  u64*   px    = (u64*)   (ws + 103000576);    // 200000*8 = 1,600,000 (end ~104.6MB)

  hipMemsetAsync(bfill, 0, NFILL * sizeof(int), stream);

  // weight folding + x packing (independent of graph work)
  pack_x<<<(cN0 + 255) / 256, 256, 0, stream>>>(x, px);
  build_wt2<<<512, KP, 0, stream>>>(SB.Win, CB.Win, SB.bin, CB.bin, Wt);
  build_small<<<128, 128, 0, stream>>>(Ws2c, Wc2s, a1p, a2p, b2p, M);
  build_G<<<512, 256, 0, stream>>>(SB.Wout, CB.Wout, M, Gt);
  build_gvec<<<1, 256, 0, stream>>>(SB.bout, CB.bout, M, gvec);

  // edge bucketing
  bucketize_v4<<<2 * NCH0 + 2 * NCH1, 512, 0, stream>>>(
      SB.e0s, SB.e0d, CB.e0s, CB.e0d, SB.e1s, SB.e1d, CB.e1s, CB.e1d,
      bfill, packed);

  // compute pipeline
  agg0_fused<<<4 * NBA0, 512, 0, stream>>>(px,
      SB.t0, SB.t1, SB.t2, SB.t3, SB.t4,
      CB.t0, CB.t1, CB.t2, CB.t3, CB.t4,
      bfill, packed, u);
  gemm_mfma2<<<4 * GEMM_RB, 256, 0, stream>>>(u, Wt, h1);
  agg1_fused<<<2 * NBA1, 256, 0, stream>>>(h1, bfill, packed, V);
  tail_gemm<<<TAIL_NB, 64, 0, stream>>>(V, Gt, gvec, (float*)d_out);
}

// Round 12
// 370.455 us; speedup vs baseline: 1.5850x; 1.0147x over previous
//
#include <hip/hip_runtime.h>

// ---------------- problem constants ----------------
constexpr int cN0 = 200000, cN1 = 50000, cN2 = 10000;
constexpr int cE0 = 800000, cE1 = 160000;
constexpr int GD  = 144;       // 32+16+16+16+64
constexpr int KP  = 160;       // padded K for MFMA (col 144 = bias-multiplier lane)
constexpr int HID = 256, OUTD = 128;
constexpr int KT  = 512;       // tail K = 2*HID

// layer-0 buckets: 256 dsts each; layer-1 buckets: 64 dsts each
constexpr int WN0  = 256, CAP0 = 4608;      // lambda=4082, +8 sigma
constexpr int WN1  = 64,  CAP1 = 1280;      // lambda~1019, +8 sigma
constexpr int CAP0Q = 1280;                 // quarter-bucket capacity (lambda~1021)
constexpr int NBA0 = (cN1 + WN0 - 1) / WN0;   // 196 buckets/branch (L0)
constexpr int NBA1 = (cN2 + WN1 - 1) / WN1;   // 157 buckets/branch (L1)
constexpr int NFILL = 2 * NBA0 + 2 * NBA1;    // 706
constexpr size_t L1PBASE = (size_t)(2 * NBA0) * CAP0;   // packed offset of L1 region

constexpr int GEMM_RB = (50048 + 255) / 256; // 196 row-blocks
constexpr int TAIL_NB = cN2 / 16;            // 625
constexpr size_t UPLANE = (size_t)50048 * KP;

constexpr int CHUNK = 8192;                      // edges per bucketize block
constexpr int NCH0  = (cE0 + CHUNK - 1) / CHUNK; // 98
constexpr int NCH1  = (cE1 + CHUNK - 1) / CHUNK; // 20

typedef __attribute__((ext_vector_type(8))) short bf16x8;
typedef __attribute__((ext_vector_type(4))) float f32x4;
typedef unsigned long long u64;

__device__ __forceinline__ ushort f2bf(float f) {
  union { float f; unsigned u; } v; v.f = f;
  unsigned r = (v.u + 0x7FFFu + ((v.u >> 16) & 1u)) >> 16;
  return (ushort)r;
}
__device__ __forceinline__ float bf2f(ushort u) {
  union { unsigned u; float f; } v; v.u = ((unsigned)u) << 16;
  return v.f;
}

// ---------------- pack x rows into u64 (5 x 10-bit fields) ----------------
__global__ __launch_bounds__(256)
void pack_x(const int* __restrict__ x, u64* __restrict__ px) {
  int i = blockIdx.x * 256 + threadIdx.x;
  if (i < cN0) {
    const int* xp = x + (size_t)i * 5;
    u64 v = (u64)(xp[0] & 1023)
          | ((u64)(xp[1] & 1023) << 10)
          | ((u64)(xp[2] & 1023) << 20)
          | ((u64)(xp[3] & 1023) << 30)
          | ((u64)(xp[4] & 1023) << 40);
    px[i] = v;
  }
}

// ---------------- bucketize v4 (unchanged) ----------------
// packed word (UNSIGNED): bits 0..17 src (<2^18), bits 18..25 local dst.
__global__ __launch_bounds__(512)
void bucketize_v4(const int* __restrict__ s0, const int* __restrict__ d0,
                  const int* __restrict__ s1, const int* __restrict__ d1,
                  const int* __restrict__ s2, const int* __restrict__ d2,
                  const int* __restrict__ s3, const int* __restrict__ d3,
                  int* __restrict__ bfill, unsigned* __restrict__ packed) {
  __shared__ ushort rawD[CHUNK];                  // 16 KB
  __shared__ unsigned sed[CHUNK];                 // 32 KB sorted edges
  __shared__ int lcnt[NBA0], lstart[NBA0], lfill[NBA0];
  int bid = blockIdx.x, tid = threadIdx.x;
  const int *sp, *dp; int E, blk, NB, shift, wmask, CAPs, fbase;
  unsigned* pb;
  if (bid < NCH0) {
    sp = s0; dp = d0; E = cE0; blk = bid;             NB = NBA0; shift = 8; wmask = 255;
    CAPs = CAP0; fbase = 0;        pb = packed;
  } else if (bid < 2 * NCH0) {
    sp = s1; dp = d1; E = cE0; blk = bid - NCH0;      NB = NBA0; shift = 8; wmask = 255;
    CAPs = CAP0; fbase = NBA0;     pb = packed + (size_t)NBA0 * CAP0;
  } else if (bid < 2 * NCH0 + NCH1) {
    sp = s2; dp = d2; E = cE1; blk = bid - 2 * NCH0;  NB = NBA1; shift = 6; wmask = 63;
    CAPs = CAP1; fbase = 2 * NBA0; pb = packed + L1PBASE;
  } else {
    sp = s3; dp = d3; E = cE1; blk = bid - 2 * NCH0 - NCH1; NB = NBA1; shift = 6; wmask = 63;
    CAPs = CAP1; fbase = 2 * NBA0 + NBA1; pb = packed + L1PBASE + (size_t)NBA1 * CAP1;
  }
  int base = blk * CHUNK;
  int n = min(CHUNK, E - base);

  for (int i = tid; i < NB; i += 512) { lcnt[i] = 0; lfill[i] = 0; }
  __syncthreads();
  for (int i = tid; i < n; i += 512) {
    int dd = dp[base + i];
    rawD[i] = (ushort)dd;
    atomicAdd(&lcnt[dd >> shift], 1);
  }
  __syncthreads();
  if (tid < 64) {
    int lane = tid;
    int i0 = lane * 4;
    int v[4], s = 0;
    #pragma unroll
    for (int j = 0; j < 4; ++j) {
      v[j] = (i0 + j < NB) ? lcnt[i0 + j] : 0;
      s += v[j];
    }
    int tot = s;
    #pragma unroll
    for (int off = 1; off < 64; off <<= 1) {
      int t = __shfl_up(s, off);
      if (lane >= off) s += t;
    }
    int excl = s - tot;
    #pragma unroll
    for (int j = 0; j < 4; ++j) {
      if (i0 + j < NB) lstart[i0 + j] = excl;
      excl += v[j];
    }
  }
  __syncthreads();
  for (int i = tid; i < n; i += 512) {
    int dd = rawD[i];
    int b = dd >> shift;
    int p = atomicAdd(&lfill[b], 1);
    sed[lstart[b] + p] = (unsigned)sp[base + i] | ((unsigned)(dd & wmask) << 18);
  }
  __syncthreads();
  int lane = tid & 63, wv = tid >> 6;
  for (int b = wv; b < NB; b += 8) {
    int cnt = lcnt[b];
    if (cnt == 0) continue;
    int gb0;
    if (lane == 0) gb0 = atomicAdd(&bfill[fbase + b], cnt);
    gb0 = __shfl(gb0, 0);
    int st = lstart[b];
    for (int i = lane; i < cnt; i += 64) {
      int gp = gb0 + i;
      if (gp < CAPs) pb[(size_t)b * CAPs + gp] = sed[st + i];
    }
  }
}

// ---------------- fused layer-0: quarter-bucket blocks (4 waves, 64 dsts) --
// grid: (br*NBA0 + bk)*4 + q ; block = 256 threads.
__global__ __launch_bounds__(256)
void agg0_fused(const u64* __restrict__ px,
                const float* __restrict__ s_t0, const float* __restrict__ s_t1,
                const float* __restrict__ s_t2, const float* __restrict__ s_t3,
                const float* __restrict__ s_t4,
                const float* __restrict__ c_t0, const float* __restrict__ c_t1,
                const float* __restrict__ c_t2, const float* __restrict__ c_t3,
                const float* __restrict__ c_t4,
                const int* __restrict__ bfill, const unsigned* __restrict__ packed,
                ushort* __restrict__ u) {
  __shared__ int lsrc[CAP0Q];                        // 5 KB
  __shared__ int lcnt[64], lstart[64], lfill[64];    // 768 B
  __shared__ u64 pxst[4][64];                        // 2 KB
  int tid = threadIdx.x, w = tid >> 6, lane = tid & 63;
  int gb = blockIdx.x >> 2;
  int q  = blockIdx.x & 3;
  int br = gb / NBA0;
  int bk = gb - br * NBA0;
  int dst0 = bk * WN0 + q * 64;
  int nd = min(64, cN1 - dst0);
  if (nd <= 0) return;

  const float* t0 = br ? c_t0 : s_t0;
  const float* t1 = br ? c_t1 : s_t1;
  const float* t2 = br ? c_t2 : s_t2;
  const float* t3 = br ? c_t3 : s_t3;
  const float* t4 = br ? c_t4 : s_t4;
  const float* gbase; int sh, gstride;
  bool has = (lane < 36);
  if (lane < 8)       { gbase = t0 + lane * 4;        sh = 0;  gstride = 32; }
  else if (lane < 12) { gbase = t1 + (lane - 8) * 4;  sh = 10; gstride = 16; }
  else if (lane < 16) { gbase = t2 + (lane - 12) * 4; sh = 20; gstride = 16; }
  else if (lane < 20) { gbase = t3 + (lane - 16) * 4; sh = 30; gstride = 16; }
  else if (lane < 36) { gbase = t4 + (lane - 20) * 4; sh = 40; gstride = 64; }
  else                { gbase = t0;                   sh = 0;  gstride = 0;  }

  if (tid < 64) { lcnt[tid] = 0; lfill[tid] = 0; }
  __syncthreads();
  int ec = min(bfill[gb], CAP0);
  const unsigned* pb = packed + (size_t)gb * CAP0;
  // pass A: count per-dst (own quarter only; quarter = bits 24-25)
  for (int i = tid; i < ec; i += 256) {
    unsigned v = pb[i];
    if (((v >> 24) & 3u) == (unsigned)q)
      atomicAdd(&lcnt[(v >> 18) & 63u], 1);
  }
  __syncthreads();
  // scan 64 bins (single wave)
  if (tid < 64) {
    int c = lcnt[tid]; int s = c;
    #pragma unroll
    for (int off = 1; off < 64; off <<= 1) {
      int t = __shfl_up(s, off);
      if (lane >= off) s += t;
    }
    lstart[tid] = s - c;
  }
  __syncthreads();
  // pass B: scatter src by dst (own quarter only)
  for (int i = tid; i < ec; i += 256) {
    unsigned v = pb[i];
    if (((v >> 24) & 3u) == (unsigned)q) {
      int l = (int)((v >> 18) & 63u);
      int p = atomicAdd(&lfill[l], 1);
      int idx = lstart[l] + p;
      if (idx < CAP0Q) lsrc[idx] = (int)(v & 0x3FFFFu);
    }
  }
  __syncthreads();

  u64* pxw = pxst[w];
  for (int d = w; d < nd; d += 4) {
    int deg = lcnt[d], beg = lstart[d];
    float4 acc = make_float4(0.f, 0.f, 0.f, 0.f);
    for (int off = 0; off < deg; off += 64) {
      int nn = min(64, deg - off);
      if (lane < nn)
        pxw[lane] = px[lsrc[beg + off + lane]];
      int e = 0;
      for (; e + 8 <= nn; e += 8) {
        int rr[8];
        #pragma unroll
        for (int qq = 0; qq < 8; ++qq)
          rr[qq] = (int)((pxw[e + qq] >> sh) & 1023ull);
        float4 g[8];
        #pragma unroll
        for (int qq = 0; qq < 8; ++qq)
          g[qq] = has ? *reinterpret_cast<const float4*>(gbase + (size_t)rr[qq] * gstride)
                      : make_float4(0.f, 0.f, 0.f, 0.f);
        #pragma unroll
        for (int qq = 0; qq < 8; ++qq) {
          acc.x += g[qq].x; acc.y += g[qq].y; acc.z += g[qq].z; acc.w += g[qq].w;
        }
      }
      for (; e < nn; ++e) {
        int r = (int)((pxw[e] >> sh) & 1023ull);
        if (has) {
          const float4 g = *reinterpret_cast<const float4*>(gbase + (size_t)r * gstride);
          acc.x += g.x; acc.y += g.y; acc.z += g.z; acc.w += g.w;
        }
      }
    }
    float invc = (deg > 0) ? 1.f / (float)deg : 0.f;
    int dg = dst0 + d;
    ushort* ur = u + (size_t)br * UPLANE + (size_t)dg * KP;
    u64 pvd = px[dg];
    if (has) {
      int rowd = (int)((pvd >> sh) & 1023ull);
      const float4 sv = *reinterpret_cast<const float4*>(gbase + (size_t)rowd * gstride);
      float4 r;
      r.x = sv.x + acc.x * invc;
      r.y = sv.y + acc.y * invc;
      r.z = sv.z + acc.z * invc;
      r.w = sv.w + acc.w * invc;
      ushort4 o;
      o.x = f2bf(r.x); o.y = f2bf(r.y); o.z = f2bf(r.z); o.w = f2bf(r.w);
      *reinterpret_cast<ushort4*>(ur + lane * 4) = o;
    } else if (lane == 36) {
      ushort4 o;
      o.x = f2bf(deg > 0 ? 2.f : 1.f);   // bias multiplier feature (col 144)
      o.y = 0; o.z = 0; o.w = 0;
      *reinterpret_cast<ushort4*>(ur + 144) = o;
    } else if (lane < 40) {
      *reinterpret_cast<ushort4*>(ur + lane * 4) = make_ushort4(0, 0, 0, 0);
    }
  }
}

// ---------------- W_in transpose+bf16+pad (+bias in row 144) ----------------
__global__ __launch_bounds__(KP)
void build_wt2(const float* __restrict__ Ws, const float* __restrict__ Wc,
               const float* __restrict__ bs, const float* __restrict__ bc,
               ushort* __restrict__ Wt) {
  int br = blockIdx.x >> 8, n = blockIdx.x & 255, k = threadIdx.x;
  const float* W = br ? Wc : Ws;
  const float* b = br ? bc : bs;
  float v = (k < GD) ? W[(size_t)k * HID + n] : ((k == GD) ? b[n] : 0.f);
  Wt[(size_t)br * HID * KP + n * KP + k] = f2bf(v);
}

// ---------------- layer-0 MFMA GEMM: h1 = relu(u@Wt^T), bf16 out -----------
__global__ __launch_bounds__(256)
void gemm_mfma2(const ushort* __restrict__ U, const ushort* __restrict__ Wt,
                ushort* __restrict__ h1) {
  __shared__ ushort Wth[128][KP + 8];
  int bid = blockIdx.x, tid = threadIdx.x;
  int rowblk = bid % GEMM_RB;
  int half = (bid / GEMM_RB) & 1;
  int br = bid / (2 * GEMM_RB);
  const ushort* Wsrc = Wt + ((size_t)br * HID + half * 128) * KP;
  for (int i = tid; i < 128 * (KP / 8); i += 256) {
    int r = i / (KP / 8), g = i - r * (KP / 8);
    *reinterpret_cast<bf16x8*>(&Wth[r][g * 8]) =
        *reinterpret_cast<const bf16x8*>(Wsrc + (size_t)r * KP + g * 8);
  }
  __syncthreads();
  int w = tid >> 6, lane = tid & 63, l15 = lane & 15, lhi = lane >> 4;
  int rowbase = rowblk * 256 + w * 64;
  const ushort* Ubr = U + (size_t)br * UPLANE;
  f32x4 acc[4][8];
  #pragma unroll
  for (int rt = 0; rt < 4; ++rt)
    #pragma unroll
    for (int ct = 0; ct < 8; ++ct) acc[rt][ct] = (f32x4){0.f, 0.f, 0.f, 0.f};
  #pragma unroll
  for (int ks = 0; ks < 5; ++ks) {
    bf16x8 bfr[8];
    #pragma unroll
    for (int ct = 0; ct < 8; ++ct)
      bfr[ct] = *reinterpret_cast<const bf16x8*>(&Wth[ct * 16 + l15][lhi * 8 + ks * 32]);
    #pragma unroll
    for (int rt = 0; rt < 4; ++rt) {
      int ar = rowbase + rt * 16 + l15;
      if (ar > 50047) ar = 50047;
      bf16x8 af = *reinterpret_cast<const bf16x8*>(Ubr + (size_t)ar * KP + lhi * 8 + ks * 32);
      #pragma unroll
      for (int ct = 0; ct < 8; ++ct)
        acc[rt][ct] = __builtin_amdgcn_mfma_f32_16x16x32_bf16(af, bfr[ct], acc[rt][ct], 0, 0, 0);
    }
  }
  ushort* h1p = h1 + (size_t)br * cN1 * HID + half * 128;
  #pragma unroll
  for (int rt = 0; rt < 4; ++rt) {
    #pragma unroll
    for (int r = 0; r < 4; ++r) {
      int row = rowbase + rt * 16 + lhi * 4 + r;
      if (row >= cN1) continue;
      #pragma unroll
      for (int ct = 0; ct < 8; ++ct)
        h1p[(size_t)row * HID + ct * 16 + l15] = f2bf(fmaxf(acc[rt][ct][r], 0.f));
    }
  }
}

// ---------------- fused layer-1: LDS sort + h1 mean-agg -> V bf16 ----------
__global__ __launch_bounds__(256)
void agg1_fused(const ushort* __restrict__ h1, const int* __restrict__ bfill,
                const unsigned* __restrict__ packed, ushort* __restrict__ V) {
  __shared__ unsigned lvals[CAP1];
  __shared__ int lsrc[CAP1];
  __shared__ int lcnt[WN1], lstart[WN1], lfill[WN1];
  int tid = threadIdx.x, w = tid >> 6, lane = tid & 63;
  int br = blockIdx.x / NBA1;
  int bk = blockIdx.x - br * NBA1;
  int fb = 2 * NBA0 + blockIdx.x;
  int dst0 = bk * WN1;
  int nd = min(WN1, cN2 - dst0);
  const ushort* h1p = h1 + (size_t)br * cN1 * HID;

  if (tid < WN1) { lcnt[tid] = 0; lfill[tid] = 0; }
  __syncthreads();
  int ec = min(bfill[fb], CAP1);
  const unsigned* pb = packed + L1PBASE + (size_t)blockIdx.x * CAP1;
  for (int i = tid; i < ec; i += 256) {
    unsigned v = pb[i];
    lvals[i] = v;
    atomicAdd(&lcnt[v >> 18], 1);
  }
  __syncthreads();
  if (tid < 64) {
    int c = lcnt[tid]; int s = c;
    #pragma unroll
    for (int off = 1; off < 64; off <<= 1) {
      int t = __shfl_up(s, off);
      if (lane >= off) s += t;
    }
    lstart[tid] = s - c;
  }
  __syncthreads();
  for (int i = tid; i < ec; i += 256) {
    unsigned v = lvals[i];
    int l = (int)(v >> 18);
    int p = atomicAdd(&lfill[l], 1);
    lsrc[lstart[l] + p] = (int)(v & 0x3FFFFu);
  }
  __syncthreads();

  for (int d = w; d < nd; d += 4) {
    int deg = lcnt[d], beg = lstart[d];
    float4 acc = make_float4(0.f, 0.f, 0.f, 0.f);
    int e = 0;
    for (; e + 4 <= deg; e += 4) {
      int sA = lsrc[beg + e], sB = lsrc[beg + e + 1];
      int sC = lsrc[beg + e + 2], sD = lsrc[beg + e + 3];
      ushort4 hA = *reinterpret_cast<const ushort4*>(h1p + (size_t)sA * HID + lane * 4);
      ushort4 hB = *reinterpret_cast<const ushort4*>(h1p + (size_t)sB * HID + lane * 4);
      ushort4 hC = *reinterpret_cast<const ushort4*>(h1p + (size_t)sC * HID + lane * 4);
      ushort4 hD = *reinterpret_cast<const ushort4*>(h1p + (size_t)sD * HID + lane * 4);
      acc.x += bf2f(hA.x) + bf2f(hB.x) + bf2f(hC.x) + bf2f(hD.x);
      acc.y += bf2f(hA.y) + bf2f(hB.y) + bf2f(hC.y) + bf2f(hD.y);
      acc.z += bf2f(hA.z) + bf2f(hB.z) + bf2f(hC.z) + bf2f(hD.z);
      acc.w += bf2f(hA.w) + bf2f(hB.w) + bf2f(hC.w) + bf2f(hD.w);
    }
    for (; e < deg; ++e) {
      int s = lsrc[beg + e];
      ushort4 hv = *reinterpret_cast<const ushort4*>(h1p + (size_t)s * HID + lane * 4);
      acc.x += bf2f(hv.x); acc.y += bf2f(hv.y); acc.z += bf2f(hv.z); acc.w += bf2f(hv.w);
    }
    float invc = (deg > 0) ? 1.f / (float)deg : 0.f;
    int dg = dst0 + d;
    ushort4 dv = *reinterpret_cast<const ushort4*>(h1p + (size_t)dg * HID + lane * 4);
    ushort4 o;
    o.x = f2bf(bf2f(dv.x) + acc.x * invc);
    o.y = f2bf(bf2f(dv.y) + acc.y * invc);
    o.z = f2bf(bf2f(dv.z) + acc.z * invc);
    o.w = f2bf(bf2f(dv.w) + acc.w * invc);
    *reinterpret_cast<ushort4*>(V + (size_t)dg * KT + br * HID + lane * 4) = o;
  }
}

// ---------------- integration weight folding ----------------
__global__ __launch_bounds__(128)
void build_small(const float* __restrict__ Ws2c, const float* __restrict__ Wc2s,
                 const float* __restrict__ a1p, const float* __restrict__ a2p,
                 const float* __restrict__ b2p, float* __restrict__ M) {
  int r = blockIdx.x, c = threadIdx.x;
  float A1 = a1p[0], A2 = a2p[0], B2 = b2p[0];
  float c0 = 1.f - A2 - B2;
  float c1 = A2 + B2 * (1.f - A1);
  float c2 = A1 * B2;
  float s1 = 0.f, s4 = 0.f;
  for (int k = 0; k < 128; ++k) {
    s1 += Ws2c[r * 128 + k] * Wc2s[k * 128 + c];
    s4 += Wc2s[r * 128 + k] * Ws2c[k * 128 + c];
  }
  float eye = (r == c) ? c0 : 0.f;
  M[0 * 16384 + r * 128 + c] = c2 * s1 + eye;
  M[1 * 16384 + r * 128 + c] = c1 * Wc2s[r * 128 + c];
  M[2 * 16384 + r * 128 + c] = c1 * Ws2c[r * 128 + c];
  M[3 * 16384 + r * 128 + c] = c2 * s4 + eye;
}

__global__ __launch_bounds__(256)
void build_G(const float* __restrict__ Wout_s, const float* __restrict__ Wout_c,
             const float* __restrict__ M, ushort* __restrict__ Gt) {
  __shared__ float wr[128];
  int k = blockIdx.x, j = threadIdx.x;
  const float* wrow = (k < 256) ? &Wout_s[(size_t)k * 128] : &Wout_c[(size_t)(k - 256) * 128];
  if (j < 128) wr[j] = wrow[j];
  __syncthreads();
  const float* Mm = (j < 128) ? (k < 256 ? M : M + 16384)
                              : (k < 256 ? M + 2 * 16384 : M + 3 * 16384);
  int jj = j & 127;
  float s = 0.f;
  for (int t = 0; t < 128; ++t) s += wr[t] * Mm[t * 128 + jj];
  Gt[(size_t)j * KT + k] = f2bf(s);
}

__global__ __launch_bounds__(256)
void build_gvec(const float* __restrict__ b_s, const float* __restrict__ b_c,
                const float* __restrict__ M, float* __restrict__ gvec) {
  int j = threadIdx.x, jj = j & 127;
  const float* Ma = (j < 128) ? M : M + 2 * 16384;
  const float* Mb = (j < 128) ? M + 16384 : M + 3 * 16384;
  float s = 0.f;
  for (int t = 0; t < 128; ++t)
    s += b_s[t] * Ma[t * 128 + jj] + b_c[t] * Mb[t * 128 + jj];
  gvec[j] = s;
}

// ---------------- tail MFMA GEMM: out = V @ Gt^T + gvec ----------------
__global__ __launch_bounds__(64)
void tail_gemm(const ushort* __restrict__ V, const ushort* __restrict__ Gt,
               const float* __restrict__ gvec, float* __restrict__ out) {
  int lane = threadIdx.x;
  int l15 = lane & 15, lhi = lane >> 4;
  int rowW = blockIdx.x * 16;
  f32x4 acc[16];
  #pragma unroll
  for (int t = 0; t < 16; ++t) acc[t] = (f32x4){0.f, 0.f, 0.f, 0.f};
  const ushort* vp = V + (size_t)(rowW + l15) * KT + lhi * 8;
  const ushort* gp = Gt + (size_t)l15 * KT + lhi * 8;
  #pragma unroll
  for (int ks = 0; ks < 16; ++ks) {
    bf16x8 a = *reinterpret_cast<const bf16x8*>(vp + ks * 32);
    #pragma unroll
    for (int t = 0; t < 16; ++t) {
      bf16x8 b = *reinterpret_cast<const bf16x8*>(gp + (size_t)t * 16 * KT + ks * 32);
      acc[t] = __builtin_amdgcn_mfma_f32_16x16x32_bf16(a, b, acc[t], 0, 0, 0);
    }
  }
  int r0 = rowW + lhi * 4;
  #pragma unroll
  for (int t = 0; t < 16; ++t) {
    int col = t * 16 + l15;
    float gv = gvec[col];
    float* dst = (col < 128) ? out + (size_t)r0 * OUTD + col
                             : out + (size_t)cN2 * OUTD + (size_t)r0 * OUTD + (col - 128);
    #pragma unroll
    for (int r = 0; r < 4; ++r)
      dst[(size_t)r * OUTD] = acc[t][r] + gv;
  }
}

// ---------------- launch ----------------
extern "C" void kernel_launch(void* const* d_in, const int* in_sizes, int n_in,
                              void* d_out, int out_size, void* d_ws, size_t ws_size,
                              hipStream_t stream) {
  const int* x = (const int*)d_in[0];
  struct Branch {
    const int *e0s, *e0d, *e1s, *e1d;
    const float *t0, *t1, *t2, *t3, *t4, *Win, *bin, *Wout, *bout;
  };
  auto mk = [&](int b) {
    Branch B;
    B.e0s = (const int*)d_in[b + 0];
    B.e0d = (const int*)d_in[b + 1];
    B.e1s = (const int*)d_in[b + 2];
    B.e1d = (const int*)d_in[b + 3];
    B.t0  = (const float*)d_in[b + 4];
    B.t1  = (const float*)d_in[b + 5];
    B.t2  = (const float*)d_in[b + 6];
    B.t3  = (const float*)d_in[b + 7];
    B.t4  = (const float*)d_in[b + 8];
    B.Win = (const float*)d_in[b + 9];
    B.bin = (const float*)d_in[b + 10];
    B.Wout= (const float*)d_in[b + 11];
    B.bout= (const float*)d_in[b + 12];
    return B;
  };
  Branch SB = mk(1), CB = mk(14);
  const float* Ws2c = (const float*)d_in[27];
  const float* Wc2s = (const float*)d_in[28];
  const float* a1p  = (const float*)d_in[29];
  const float* a2p  = (const float*)d_in[30];
  const float* b2p  = (const float*)d_in[31];

  // workspace layout
  char* ws = (char*)d_ws;
  ushort* u    = (ushort*)(ws + 0);            // 2*50048*160*2 = 32,030,720
  ushort* h1   = (ushort*)(ws + 32030720);     // 2*50000*256*2 = 51,200,000
  ushort* V    = (ushort*)(ws + 83230720);     // 10000*512*2   = 10,240,000
  float*  M    = (float*) (ws + 93470720);     // 262,144
  ushort* Gt   = (ushort*)(ws + 93732864);     // 262,144
  float*  gvec = (float*) (ws + 93995008);     // 1,024
  ushort* Wt   = (ushort*)(ws + 93996032);     // 163,840
  int*   bfill = (int*)   (ws + 94159872);     // 706*4 (pad to 7,680)
  unsigned* packed = (unsigned*)(ws + 94167552); // 8,833,024
  u64*   px    = (u64*)   (ws + 103000576);    // 200000*8 = 1,600,000 (end ~104.6MB)

  hipMemsetAsync(bfill, 0, NFILL * sizeof(int), stream);

  // weight folding + x packing (independent of graph work)
  pack_x<<<(cN0 + 255) / 256, 256, 0, stream>>>(x, px);
  build_wt2<<<512, KP, 0, stream>>>(SB.Win, CB.Win, SB.bin, CB.bin, Wt);
  build_small<<<128, 128, 0, stream>>>(Ws2c, Wc2s, a1p, a2p, b2p, M);
  build_G<<<512, 256, 0, stream>>>(SB.Wout, CB.Wout, M, Gt);
  build_gvec<<<1, 256, 0, stream>>>(SB.bout, CB.bout, M, gvec);

  // edge bucketing
  bucketize_v4<<<2 * NCH0 + 2 * NCH1, 512, 0, stream>>>(
      SB.e0s, SB.e0d, CB.e0s, CB.e0d, SB.e1s, SB.e1d, CB.e1s, CB.e1d,
      bfill, packed);

  // compute pipeline
  agg0_fused<<<8 * NBA0, 256, 0, stream>>>(px,
      SB.t0, SB.t1, SB.t2, SB.t3, SB.t4,
      CB.t0, CB.t1, CB.t2, CB.t3, CB.t4,
      bfill, packed, u);
  gemm_mfma2<<<4 * GEMM_RB, 256, 0, stream>>>(u, Wt, h1);
  agg1_fused<<<2 * NBA1, 256, 0, stream>>>(h1, bfill, packed, V);
  tail_gemm<<<TAIL_NB, 64, 0, stream>>>(V, Gt, gvec, (float*)d_out);
}

// Round 13
// 287.571 us; speedup vs baseline: 2.0418x; 1.2882x over previous
//
#include <hip/hip_runtime.h>

// ---------------- problem constants ----------------
constexpr int cN0 = 200000, cN1 = 50000, cN2 = 10000;
constexpr int cE0 = 800000, cE1 = 160000;
constexpr int GD  = 144;       // 32+16+16+16+64
constexpr int KP  = 160;       // padded K for MFMA (col 144 = bias-multiplier lane)
constexpr int HID = 256, OUTD = 128;
constexpr int KT  = 512;       // tail K = 2*HID

// layer-0 buckets: 256 dsts each; layer-1 buckets: 64 dsts each
constexpr int WN0  = 256, CAP0 = 4608;      // lambda=4082, +8 sigma
constexpr int WN1  = 64,  CAP1 = 1280;      // lambda~1019, +8 sigma
constexpr int CAP0Q = 1280;                 // quarter-bucket capacity (lambda~1021)
constexpr int NBA0 = (cN1 + WN0 - 1) / WN0;   // 196 buckets/branch (L0)
constexpr int NBA1 = (cN2 + WN1 - 1) / WN1;   // 157 buckets/branch (L1)
constexpr int NFILL = 2 * NBA0 + 2 * NBA1;    // 706
constexpr size_t L1PBASE = (size_t)(2 * NBA0) * CAP0;   // packed offset of L1 region

constexpr int GEMM_RB = (50048 + 255) / 256; // 196 row-blocks
constexpr int TAIL_NB = cN2 / 16;            // 625
constexpr size_t UPLANE = (size_t)50048 * KP;

constexpr int CHUNK = 8192;                      // edges per bucketize block
constexpr int NCH0  = (cE0 + CHUNK - 1) / CHUNK; // 98
constexpr int NCH1  = (cE1 + CHUNK - 1) / CHUNK; // 20

typedef __attribute__((ext_vector_type(8))) short bf16x8;
typedef __attribute__((ext_vector_type(4))) float f32x4;
typedef unsigned long long u64;

__device__ __forceinline__ ushort f2bf(float f) {
  union { float f; unsigned u; } v; v.f = f;
  unsigned r = (v.u + 0x7FFFu + ((v.u >> 16) & 1u)) >> 16;
  return (ushort)r;
}
__device__ __forceinline__ float bf2f(ushort u) {
  union { unsigned u; float f; } v; v.u = ((unsigned)u) << 16;
  return v.f;
}

// ---------------- pack x rows into u64 (5 x 10-bit fields) ----------------
__global__ __launch_bounds__(256)
void pack_x(const int* __restrict__ x, u64* __restrict__ px) {
  int i = blockIdx.x * 256 + threadIdx.x;
  if (i < cN0) {
    const int* xp = x + (size_t)i * 5;
    u64 v = (u64)(xp[0] & 1023)
          | ((u64)(xp[1] & 1023) << 10)
          | ((u64)(xp[2] & 1023) << 20)
          | ((u64)(xp[3] & 1023) << 30)
          | ((u64)(xp[4] & 1023) << 40);
    px[i] = v;
  }
}

// ---------------- bucketize v5: batched loads + parallel phase-4 atomics ---
// packed word (UNSIGNED): bits 0..17 src (<2^18), bits 18..25 local dst.
__global__ __launch_bounds__(512)
void bucketize_v5(const int* __restrict__ s0, const int* __restrict__ d0,
                  const int* __restrict__ s1, const int* __restrict__ d1,
                  const int* __restrict__ s2, const int* __restrict__ d2,
                  const int* __restrict__ s3, const int* __restrict__ d3,
                  int* __restrict__ bfill, unsigned* __restrict__ packed) {
  __shared__ ushort rawD[CHUNK];                  // 16 KB
  __shared__ unsigned sed[CHUNK];                 // 32 KB sorted edges
  __shared__ int lcnt[NBA0], lstart[NBA0], lfill[NBA0], gbase_s[NBA0];
  int bid = blockIdx.x, tid = threadIdx.x;
  const int *sp, *dp; int E, blk, NB, shift, wmask, CAPs, fbase;
  unsigned* pb;
  if (bid < NCH0) {
    sp = s0; dp = d0; E = cE0; blk = bid;             NB = NBA0; shift = 8; wmask = 255;
    CAPs = CAP0; fbase = 0;        pb = packed;
  } else if (bid < 2 * NCH0) {
    sp = s1; dp = d1; E = cE0; blk = bid - NCH0;      NB = NBA0; shift = 8; wmask = 255;
    CAPs = CAP0; fbase = NBA0;     pb = packed + (size_t)NBA0 * CAP0;
  } else if (bid < 2 * NCH0 + NCH1) {
    sp = s2; dp = d2; E = cE1; blk = bid - 2 * NCH0;  NB = NBA1; shift = 6; wmask = 63;
    CAPs = CAP1; fbase = 2 * NBA0; pb = packed + L1PBASE;
  } else {
    sp = s3; dp = d3; E = cE1; blk = bid - 2 * NCH0 - NCH1; NB = NBA1; shift = 6; wmask = 63;
    CAPs = CAP1; fbase = 2 * NBA0 + NBA1; pb = packed + L1PBASE + (size_t)NBA1 * CAP1;
  }
  int base = blk * CHUNK;
  int n = min(CHUNK, E - base);

  for (int i = tid; i < NB; i += 512) { lcnt[i] = 0; lfill[i] = 0; }
  __syncthreads();
  // phase 1: batch all 16 dst loads into registers, then count
  {
    int dds[16];
    #pragma unroll
    for (int k = 0; k < 16; ++k) {
      int i = tid + k * 512;
      dds[k] = (i < n) ? dp[base + i] : -1;
    }
    #pragma unroll
    for (int k = 0; k < 16; ++k) {
      int i = tid + k * 512;
      if (i < n) {
        rawD[i] = (ushort)dds[k];
        atomicAdd(&lcnt[dds[k] >> shift], 1);
      }
    }
  }
  __syncthreads();
  // phase 2: single-wave exclusive scan (64 lanes x 4 bins >= NB)
  if (tid < 64) {
    int lane = tid;
    int i0 = lane * 4;
    int v[4], s = 0;
    #pragma unroll
    for (int j = 0; j < 4; ++j) {
      v[j] = (i0 + j < NB) ? lcnt[i0 + j] : 0;
      s += v[j];
    }
    int tot = s;
    #pragma unroll
    for (int off = 1; off < 64; off <<= 1) {
      int t = __shfl_up(s, off);
      if (lane >= off) s += t;
    }
    int excl = s - tot;
    #pragma unroll
    for (int j = 0; j < 4; ++j) {
      if (i0 + j < NB) lstart[i0 + j] = excl;
      excl += v[j];
    }
  }
  __syncthreads();
  // phase 3: batch all 16 src loads, then scatter into LDS bucket order
  {
    int srcs[16];
    #pragma unroll
    for (int k = 0; k < 16; ++k) {
      int i = tid + k * 512;
      srcs[k] = (i < n) ? sp[base + i] : 0;
    }
    #pragma unroll
    for (int k = 0; k < 16; ++k) {
      int i = tid + k * 512;
      if (i < n) {
        int dd = rawD[i];
        int b = dd >> shift;
        int p = atomicAdd(&lfill[b], 1);
        sed[lstart[b] + p] = (unsigned)srcs[k] | ((unsigned)(dd & wmask) << 18);
      }
    }
  }
  __syncthreads();
  // phase 4a: ALL per-bucket global atomics issued in parallel (one/thread)
  if (tid < NB) {
    int cnt = lcnt[tid];
    gbase_s[tid] = (cnt > 0) ? atomicAdd(&bfill[fbase + tid], cnt) : 0;
  }
  __syncthreads();
  // phase 4b: contiguous run copy-out (no atomic latency in loop)
  int lane = tid & 63, wv = tid >> 6;
  for (int b = wv; b < NB; b += 8) {
    int cnt = lcnt[b];
    if (cnt == 0) continue;
    int gb0 = gbase_s[b];
    int st = lstart[b];
    for (int i = lane; i < cnt; i += 64) {
      int gp = gb0 + i;
      if (gp < CAPs) pb[(size_t)b * CAPs + gp] = sed[st + i];
    }
  }
}

// ---------------- fused layer-0: quarter-bucket blocks (4 waves, 64 dsts) --
// grid: (br*NBA0 + bk)*4 + q ; block = 256 threads.
__global__ __launch_bounds__(256)
void agg0_fused(const u64* __restrict__ px,
                const float* __restrict__ s_t0, const float* __restrict__ s_t1,
                const float* __restrict__ s_t2, const float* __restrict__ s_t3,
                const float* __restrict__ s_t4,
                const float* __restrict__ c_t0, const float* __restrict__ c_t1,
                const float* __restrict__ c_t2, const float* __restrict__ c_t3,
                const float* __restrict__ c_t4,
                const int* __restrict__ bfill, const unsigned* __restrict__ packed,
                ushort* __restrict__ u) {
  __shared__ int lsrc[CAP0Q];                        // 5 KB
  __shared__ int lcnt[64], lstart[64], lfill[64];    // 768 B
  __shared__ u64 pxst[4][64];                        // 2 KB
  int tid = threadIdx.x, w = tid >> 6, lane = tid & 63;
  int gb = blockIdx.x >> 2;
  int q  = blockIdx.x & 3;
  int br = gb / NBA0;
  int bk = gb - br * NBA0;
  int dst0 = bk * WN0 + q * 64;
  int nd = min(64, cN1 - dst0);
  if (nd <= 0) return;

  const float* t0 = br ? c_t0 : s_t0;
  const float* t1 = br ? c_t1 : s_t1;
  const float* t2 = br ? c_t2 : s_t2;
  const float* t3 = br ? c_t3 : s_t3;
  const float* t4 = br ? c_t4 : s_t4;
  const float* gbase; int sh, gstride;
  bool has = (lane < 36);
  if (lane < 8)       { gbase = t0 + lane * 4;        sh = 0;  gstride = 32; }
  else if (lane < 12) { gbase = t1 + (lane - 8) * 4;  sh = 10; gstride = 16; }
  else if (lane < 16) { gbase = t2 + (lane - 12) * 4; sh = 20; gstride = 16; }
  else if (lane < 20) { gbase = t3 + (lane - 16) * 4; sh = 30; gstride = 16; }
  else if (lane < 36) { gbase = t4 + (lane - 20) * 4; sh = 40; gstride = 64; }
  else                { gbase = t0;                   sh = 0;  gstride = 0;  }

  if (tid < 64) { lcnt[tid] = 0; lfill[tid] = 0; }
  __syncthreads();
  int ec = min(bfill[gb], CAP0);
  const unsigned* pb = packed + (size_t)gb * CAP0;
  // pass A: count per-dst (own quarter only; quarter = bits 24-25)
  for (int i = tid; i < ec; i += 256) {
    unsigned v = pb[i];
    if (((v >> 24) & 3u) == (unsigned)q)
      atomicAdd(&lcnt[(v >> 18) & 63u], 1);
  }
  __syncthreads();
  // scan 64 bins (single wave)
  if (tid < 64) {
    int c = lcnt[tid]; int s = c;
    #pragma unroll
    for (int off = 1; off < 64; off <<= 1) {
      int t = __shfl_up(s, off);
      if (lane >= off) s += t;
    }
    lstart[tid] = s - c;
  }
  __syncthreads();
  // pass B: scatter src by dst (own quarter only)
  for (int i = tid; i < ec; i += 256) {
    unsigned v = pb[i];
    if (((v >> 24) & 3u) == (unsigned)q) {
      int l = (int)((v >> 18) & 63u);
      int p = atomicAdd(&lfill[l], 1);
      int idx = lstart[l] + p;
      if (idx < CAP0Q) lsrc[idx] = (int)(v & 0x3FFFFu);
    }
  }
  __syncthreads();

  u64* pxw = pxst[w];
  for (int d = w; d < nd; d += 4) {
    int deg = lcnt[d], beg = lstart[d];
    float4 acc = make_float4(0.f, 0.f, 0.f, 0.f);
    for (int off = 0; off < deg; off += 64) {
      int nn = min(64, deg - off);
      if (lane < nn)
        pxw[lane] = px[lsrc[beg + off + lane]];
      int e = 0;
      for (; e + 8 <= nn; e += 8) {
        int rr[8];
        #pragma unroll
        for (int qq = 0; qq < 8; ++qq)
          rr[qq] = (int)((pxw[e + qq] >> sh) & 1023ull);
        float4 g[8];
        #pragma unroll
        for (int qq = 0; qq < 8; ++qq)
          g[qq] = has ? *reinterpret_cast<const float4*>(gbase + (size_t)rr[qq] * gstride)
                      : make_float4(0.f, 0.f, 0.f, 0.f);
        #pragma unroll
        for (int qq = 0; qq < 8; ++qq) {
          acc.x += g[qq].x; acc.y += g[qq].y; acc.z += g[qq].z; acc.w += g[qq].w;
        }
      }
      for (; e < nn; ++e) {
        int r = (int)((pxw[e] >> sh) & 1023ull);
        if (has) {
          const float4 g = *reinterpret_cast<const float4*>(gbase + (size_t)r * gstride);
          acc.x += g.x; acc.y += g.y; acc.z += g.z; acc.w += g.w;
        }
      }
    }
    float invc = (deg > 0) ? 1.f / (float)deg : 0.f;
    int dg = dst0 + d;
    ushort* ur = u + (size_t)br * UPLANE + (size_t)dg * KP;
    u64 pvd = px[dg];
    if (has) {
      int rowd = (int)((pvd >> sh) & 1023ull);
      const float4 sv = *reinterpret_cast<const float4*>(gbase + (size_t)rowd * gstride);
      float4 r;
      r.x = sv.x + acc.x * invc;
      r.y = sv.y + acc.y * invc;
      r.z = sv.z + acc.z * invc;
      r.w = sv.w + acc.w * invc;
      ushort4 o;
      o.x = f2bf(r.x); o.y = f2bf(r.y); o.z = f2bf(r.z); o.w = f2bf(r.w);
      *reinterpret_cast<ushort4*>(ur + lane * 4) = o;
    } else if (lane == 36) {
      ushort4 o;
      o.x = f2bf(deg > 0 ? 2.f : 1.f);   // bias multiplier feature (col 144)
      o.y = 0; o.z = 0; o.w = 0;
      *reinterpret_cast<ushort4*>(ur + 144) = o;
    } else if (lane < 40) {
      *reinterpret_cast<ushort4*>(ur + lane * 4) = make_ushort4(0, 0, 0, 0);
    }
  }
}

// ---------------- W_in transpose+bf16+pad (+bias in row 144) ----------------
__global__ __launch_bounds__(KP)
void build_wt2(const float* __restrict__ Ws, const float* __restrict__ Wc,
               const float* __restrict__ bs, const float* __restrict__ bc,
               ushort* __restrict__ Wt) {
  int br = blockIdx.x >> 8, n = blockIdx.x & 255, k = threadIdx.x;
  const float* W = br ? Wc : Ws;
  const float* b = br ? bc : bs;
  float v = (k < GD) ? W[(size_t)k * HID + n] : ((k == GD) ? b[n] : 0.f);
  Wt[(size_t)br * HID * KP + n * KP + k] = f2bf(v);
}

// ---------------- layer-0 MFMA GEMM: h1 = relu(u@Wt^T), bf16 out -----------
__global__ __launch_bounds__(256)
void gemm_mfma2(const ushort* __restrict__ U, const ushort* __restrict__ Wt,
                ushort* __restrict__ h1) {
  __shared__ ushort Wth[128][KP + 8];
  int bid = blockIdx.x, tid = threadIdx.x;
  int rowblk = bid % GEMM_RB;
  int half = (bid / GEMM_RB) & 1;
  int br = bid / (2 * GEMM_RB);
  const ushort* Wsrc = Wt + ((size_t)br * HID + half * 128) * KP;
  for (int i = tid; i < 128 * (KP / 8); i += 256) {
    int r = i / (KP / 8), g = i - r * (KP / 8);
    *reinterpret_cast<bf16x8*>(&Wth[r][g * 8]) =
        *reinterpret_cast<const bf16x8*>(Wsrc + (size_t)r * KP + g * 8);
  }
  __syncthreads();
  int w = tid >> 6, lane = tid & 63, l15 = lane & 15, lhi = lane >> 4;
  int rowbase = rowblk * 256 + w * 64;
  const ushort* Ubr = U + (size_t)br * UPLANE;
  f32x4 acc[4][8];
  #pragma unroll
  for (int rt = 0; rt < 4; ++rt)
    #pragma unroll
    for (int ct = 0; ct < 8; ++ct) acc[rt][ct] = (f32x4){0.f, 0.f, 0.f, 0.f};
  #pragma unroll
  for (int ks = 0; ks < 5; ++ks) {
    bf16x8 bfr[8];
    #pragma unroll
    for (int ct = 0; ct < 8; ++ct)
      bfr[ct] = *reinterpret_cast<const bf16x8*>(&Wth[ct * 16 + l15][lhi * 8 + ks * 32]);
    #pragma unroll
    for (int rt = 0; rt < 4; ++rt) {
      int ar = rowbase + rt * 16 + l15;
      if (ar > 50047) ar = 50047;
      bf16x8 af = *reinterpret_cast<const bf16x8*>(Ubr + (size_t)ar * KP + lhi * 8 + ks * 32);
      #pragma unroll
      for (int ct = 0; ct < 8; ++ct)
        acc[rt][ct] = __builtin_amdgcn_mfma_f32_16x16x32_bf16(af, bfr[ct], acc[rt][ct], 0, 0, 0);
    }
  }
  ushort* h1p = h1 + (size_t)br * cN1 * HID + half * 128;
  #pragma unroll
  for (int rt = 0; rt < 4; ++rt) {
    #pragma unroll
    for (int r = 0; r < 4; ++r) {
      int row = rowbase + rt * 16 + lhi * 4 + r;
      if (row >= cN1) continue;
      #pragma unroll
      for (int ct = 0; ct < 8; ++ct)
        h1p[(size_t)row * HID + ct * 16 + l15] = f2bf(fmaxf(acc[rt][ct][r], 0.f));
    }
  }
}

// ---------------- fused layer-1: LDS sort + h1 mean-agg -> V bf16 ----------
__global__ __launch_bounds__(256)
void agg1_fused(const ushort* __restrict__ h1, const int* __restrict__ bfill,
                const unsigned* __restrict__ packed, ushort* __restrict__ V) {
  __shared__ unsigned lvals[CAP1];
  __shared__ int lsrc[CAP1];
  __shared__ int lcnt[WN1], lstart[WN1], lfill[WN1];
  int tid = threadIdx.x, w = tid >> 6, lane = tid & 63;
  int br = blockIdx.x / NBA1;
  int bk = blockIdx.x - br * NBA1;
  int fb = 2 * NBA0 + blockIdx.x;
  int dst0 = bk * WN1;
  int nd = min(WN1, cN2 - dst0);
  const ushort* h1p = h1 + (size_t)br * cN1 * HID;

  if (tid < WN1) { lcnt[tid] = 0; lfill[tid] = 0; }
  __syncthreads();
  int ec = min(bfill[fb], CAP1);
  const unsigned* pb = packed + L1PBASE + (size_t)blockIdx.x * CAP1;
  for (int i = tid; i < ec; i += 256) {
    unsigned v = pb[i];
    lvals[i] = v;
    atomicAdd(&lcnt[v >> 18], 1);
  }
  __syncthreads();
  if (tid < 64) {
    int c = lcnt[tid]; int s = c;
    #pragma unroll
    for (int off = 1; off < 64; off <<= 1) {
      int t = __shfl_up(s, off);
      if (lane >= off) s += t;
    }
    lstart[tid] = s - c;
  }
  __syncthreads();
  for (int i = tid; i < ec; i += 256) {
    unsigned v = lvals[i];
    int l = (int)(v >> 18);
    int p = atomicAdd(&lfill[l], 1);
    lsrc[lstart[l] + p] = (int)(v & 0x3FFFFu);
  }
  __syncthreads();

  for (int d = w; d < nd; d += 4) {
    int deg = lcnt[d], beg = lstart[d];
    float4 acc = make_float4(0.f, 0.f, 0.f, 0.f);
    int e = 0;
    for (; e + 4 <= deg; e += 4) {
      int sA = lsrc[beg + e], sB = lsrc[beg + e + 1];
      int sC = lsrc[beg + e + 2], sD = lsrc[beg + e + 3];
      ushort4 hA = *reinterpret_cast<const ushort4*>(h1p + (size_t)sA * HID + lane * 4);
      ushort4 hB = *reinterpret_cast<const ushort4*>(h1p + (size_t)sB * HID + lane * 4);
      ushort4 hC = *reinterpret_cast<const ushort4*>(h1p + (size_t)sC * HID + lane * 4);
      ushort4 hD = *reinterpret_cast<const ushort4*>(h1p + (size_t)sD * HID + lane * 4);
      acc.x += bf2f(hA.x) + bf2f(hB.x) + bf2f(hC.x) + bf2f(hD.x);
      acc.y += bf2f(hA.y) + bf2f(hB.y) + bf2f(hC.y) + bf2f(hD.y);
      acc.z += bf2f(hA.z) + bf2f(hB.z) + bf2f(hC.z) + bf2f(hD.z);
      acc.w += bf2f(hA.w) + bf2f(hB.w) + bf2f(hC.w) + bf2f(hD.w);
    }
    for (; e < deg; ++e) {
      int s = lsrc[beg + e];
      ushort4 hv = *reinterpret_cast<const ushort4*>(h1p + (size_t)s * HID + lane * 4);
      acc.x += bf2f(hv.x); acc.y += bf2f(hv.y); acc.z += bf2f(hv.z); acc.w += bf2f(hv.w);
    }
    float invc = (deg > 0) ? 1.f / (float)deg : 0.f;
    int dg = dst0 + d;
    ushort4 dv = *reinterpret_cast<const ushort4*>(h1p + (size_t)dg * HID + lane * 4);
    ushort4 o;
    o.x = f2bf(bf2f(dv.x) + acc.x * invc);
    o.y = f2bf(bf2f(dv.y) + acc.y * invc);
    o.z = f2bf(bf2f(dv.z) + acc.z * invc);
    o.w = f2bf(bf2f(dv.w) + acc.w * invc);
    *reinterpret_cast<ushort4*>(V + (size_t)dg * KT + br * HID + lane * 4) = o;
  }
}

// ---------------- integration weight folding ----------------
__global__ __launch_bounds__(128)
void build_small(const float* __restrict__ Ws2c, const float* __restrict__ Wc2s,
                 const float* __restrict__ a1p, const float* __restrict__ a2p,
                 const float* __restrict__ b2p, float* __restrict__ M) {
  int r = blockIdx.x, c = threadIdx.x;
  float A1 = a1p[0], A2 = a2p[0], B2 = b2p[0];
  float c0 = 1.f - A2 - B2;
  float c1 = A2 + B2 * (1.f - A1);
  float c2 = A1 * B2;
  float s1 = 0.f, s4 = 0.f;
  for (int k = 0; k < 128; ++k) {
    s1 += Ws2c[r * 128 + k] * Wc2s[k * 128 + c];
    s4 += Wc2s[r * 128 + k] * Ws2c[k * 128 + c];
  }
  float eye = (r == c) ? c0 : 0.f;
  M[0 * 16384 + r * 128 + c] = c2 * s1 + eye;
  M[1 * 16384 + r * 128 + c] = c1 * Wc2s[r * 128 + c];
  M[2 * 16384 + r * 128 + c] = c1 * Ws2c[r * 128 + c];
  M[3 * 16384 + r * 128 + c] = c2 * s4 + eye;
}

__global__ __launch_bounds__(256)
void build_G(const float* __restrict__ Wout_s, const float* __restrict__ Wout_c,
             const float* __restrict__ M, ushort* __restrict__ Gt) {
  __shared__ float wr[128];
  int k = blockIdx.x, j = threadIdx.x;
  const float* wrow = (k < 256) ? &Wout_s[(size_t)k * 128] : &Wout_c[(size_t)(k - 256) * 128];
  if (j < 128) wr[j] = wrow[j];
  __syncthreads();
  const float* Mm = (j < 128) ? (k < 256 ? M : M + 16384)
                              : (k < 256 ? M + 2 * 16384 : M + 3 * 16384);
  int jj = j & 127;
  float s = 0.f;
  for (int t = 0; t < 128; ++t) s += wr[t] * Mm[t * 128 + jj];
  Gt[(size_t)j * KT + k] = f2bf(s);
}

__global__ __launch_bounds__(256)
void build_gvec(const float* __restrict__ b_s, const float* __restrict__ b_c,
                const float* __restrict__ M, float* __restrict__ gvec) {
  int j = threadIdx.x, jj = j & 127;
  const float* Ma = (j < 128) ? M : M + 2 * 16384;
  const float* Mb = (j < 128) ? M + 16384 : M + 3 * 16384;
  float s = 0.f;
  for (int t = 0; t < 128; ++t)
    s += b_s[t] * Ma[t * 128 + jj] + b_c[t] * Mb[t * 128 + jj];
  gvec[j] = s;
}

// ---------------- tail MFMA GEMM: out = V @ Gt^T + gvec ----------------
__global__ __launch_bounds__(64)
void tail_gemm(const ushort* __restrict__ V, const ushort* __restrict__ Gt,
               const float* __restrict__ gvec, float* __restrict__ out) {
  int lane = threadIdx.x;
  int l15 = lane & 15, lhi = lane >> 4;
  int rowW = blockIdx.x * 16;
  f32x4 acc[16];
  #pragma unroll
  for (int t = 0; t < 16; ++t) acc[t] = (f32x4){0.f, 0.f, 0.f, 0.f};
  const ushort* vp = V + (size_t)(rowW + l15) * KT + lhi * 8;
  const ushort* gp = Gt + (size_t)l15 * KT + lhi * 8;
  #pragma unroll
  for (int ks = 0; ks < 16; ++ks) {
    bf16x8 a = *reinterpret_cast<const bf16x8*>(vp + ks * 32);
    #pragma unroll
    for (int t = 0; t < 16; ++t) {
      bf16x8 b = *reinterpret_cast<const bf16x8*>(gp + (size_t)t * 16 * KT + ks * 32);
      acc[t] = __builtin_amdgcn_mfma_f32_16x16x32_bf16(a, b, acc[t], 0, 0, 0);
    }
  }
  int r0 = rowW + lhi * 4;
  #pragma unroll
  for (int t = 0; t < 16; ++t) {
    int col = t * 16 + l15;
    float gv = gvec[col];
    float* dst = (col < 128) ? out + (size_t)r0 * OUTD + col
                             : out + (size_t)cN2 * OUTD + (size_t)r0 * OUTD + (col - 128);
    #pragma unroll
    for (int r = 0; r < 4; ++r)
      dst[(size_t)r * OUTD] = acc[t][r] + gv;
  }
}

// ---------------- launch ----------------
extern "C" void kernel_launch(void* const* d_in, const int* in_sizes, int n_in,
                              void* d_out, int out_size, void* d_ws, size_t ws_size,
                              hipStream_t stream) {
  const int* x = (const int*)d_in[0];
  struct Branch {
    const int *e0s, *e0d, *e1s, *e1d;
    const float *t0, *t1, *t2, *t3, *t4, *Win, *bin, *Wout, *bout;
  };
  auto mk = [&](int b) {
    Branch B;
    B.e0s = (const int*)d_in[b + 0];
    B.e0d = (const int*)d_in[b + 1];
    B.e1s = (const int*)d_in[b + 2];
    B.e1d = (const int*)d_in[b + 3];
    B.t0  = (const float*)d_in[b + 4];
    B.t1  = (const float*)d_in[b + 5];
    B.t2  = (const float*)d_in[b + 6];
    B.t3  = (const float*)d_in[b + 7];
    B.t4  = (const float*)d_in[b + 8];
    B.Win = (const float*)d_in[b + 9];
    B.bin = (const float*)d_in[b + 10];
    B.Wout= (const float*)d_in[b + 11];
    B.bout= (const float*)d_in[b + 12];
    return B;
  };
  Branch SB = mk(1), CB = mk(14);
  const float* Ws2c = (const float*)d_in[27];
  const float* Wc2s = (const float*)d_in[28];
  const float* a1p  = (const float*)d_in[29];
  const float* a2p  = (const float*)d_in[30];
  const float* b2p  = (const float*)d_in[31];

  // workspace layout
  char* ws = (char*)d_ws;
  ushort* u    = (ushort*)(ws + 0);            // 2*50048*160*2 = 32,030,720
  ushort* h1   = (ushort*)(ws + 32030720);     // 2*50000*256*2 = 51,200,000
  ushort* V    = (ushort*)(ws + 83230720);     // 10000*512*2   = 10,240,000
  float*  M    = (float*) (ws + 93470720);     // 262,144
  ushort* Gt   = (ushort*)(ws + 93732864);     // 262,144
  float*  gvec = (float*) (ws + 93995008);     // 1,024
  ushort* Wt   = (ushort*)(ws + 93996032);     // 163,840
  int*   bfill = (int*)   (ws + 94159872);     // 706*4 (pad to 7,680)
  unsigned* packed = (unsigned*)(ws + 94167552); // 8,833,024
  u64*   px    = (u64*)   (ws + 103000576);    // 200000*8 = 1,600,000 (end ~104.6MB)

  hipMemsetAsync(bfill, 0, NFILL * sizeof(int), stream);

  // weight folding + x packing (independent of graph work)
  pack_x<<<(cN0 + 255) / 256, 256, 0, stream>>>(x, px);
  build_wt2<<<512, KP, 0, stream>>>(SB.Win, CB.Win, SB.bin, CB.bin, Wt);
  build_small<<<128, 128, 0, stream>>>(Ws2c, Wc2s, a1p, a2p, b2p, M);
  build_G<<<512, 256, 0, stream>>>(SB.Wout, CB.Wout, M, Gt);
  build_gvec<<<1, 256, 0, stream>>>(SB.bout, CB.bout, M, gvec);

  // edge bucketing
  bucketize_v5<<<2 * NCH0 + 2 * NCH1, 512, 0, stream>>>(
      SB.e0s, SB.e0d, CB.e0s, CB.e0d, SB.e1s, SB.e1d, CB.e1s, CB.e1d,
      bfill, packed);

  // compute pipeline
  agg0_fused<<<8 * NBA0, 256, 0, stream>>>(px,
      SB.t0, SB.t1, SB.t2, SB.t3, SB.t4,
      CB.t0, CB.t1, CB.t2, CB.t3, CB.t4,
      bfill, packed, u);
  gemm_mfma2<<<4 * GEMM_RB, 256, 0, stream>>>(u, Wt, h1);
  agg1_fused<<<2 * NBA1, 256, 0, stream>>>(h1, bfill, packed, V);
  tail_gemm<<<TAIL_NB, 64, 0, stream>>>(V, Gt, gvec, (float*)d_out);
}